// Round 1
// baseline (303.745 us; speedup 1.0000x reference)
//
#include <hip/hip_runtime.h>

typedef unsigned short u16;
typedef unsigned int u32;
typedef __attribute__((ext_vector_type(4))) float floatx4;
typedef __attribute__((ext_vector_type(8))) __bf16 bf16x8;

#define MFMA_BF16(a, b, c) __builtin_amdgcn_mfma_f32_16x16x32_bf16((a), (b), (c), 0, 0, 0)

typedef const __attribute__((address_space(1))) void* gas_ptr;
typedef __attribute__((address_space(3))) void* las_ptr;

__device__ __forceinline__ void gll16(const void* g, void* l) {
  __builtin_amdgcn_global_load_lds((gas_ptr)g, (las_ptr)l, 16, 0, 0);
}

__device__ __forceinline__ u16 f2bf(float x) {
  u32 u = __builtin_bit_cast(u32, x);
  u = (u + 0x7fffu + ((u >> 16) & 1u)) >> 16;
  return (u16)u;
}

// ---------------------------------------------------------------------------
// Kernel 1: down/up vectors from palette.
// ---------------------------------------------------------------------------
__global__ void prep_downup(const float* __restrict__ pal,
                            const float* __restrict__ qd, const float* __restrict__ qu,
                            const float* __restrict__ kd, const float* __restrict__ ku,
                            const float* __restrict__ vd, const float* __restrict__ vu,
                            const float* __restrict__ od, const float* __restrict__ ou,
                            float* __restrict__ down_f, float* __restrict__ up_f) {
  int tid = blockIdx.x * blockDim.x + threadIdx.x;
  int w = tid / 10240;
  int rem = tid - w * 10240;
  const float* dsrc = (w == 0) ? qd : (w == 1) ? kd : (w == 2) ? vd : od;
  const float* usrc = (w == 0) ? qu : (w == 1) ? ku : (w == 2) ? vu : ou;
  bool isdown = rem < 5120;
  int row = isdown ? rem : rem - 5120;
  const float* src = (isdown ? dsrc : usrc) + row * 15;
  float s = 0.f;
#pragma unroll
  for (int p = 0; p < 15; ++p) s += pal[p] * src[p];
  if (isdown) down_f[w * 5120 + row] = s;
  else        up_f[w * 5120 + row] = s;
}

// ---------------------------------------------------------------------------
// Kernel 2: W_eff[n][k] = W[n][k] + sum_r up[n][r]*down[r][k], cast to bf16.
// ---------------------------------------------------------------------------
__global__ void build_weff(const float* __restrict__ Wq, const float* __restrict__ Wk,
                           const float* __restrict__ Wv, const float* __restrict__ Wo,
                           const float* __restrict__ down_f, const float* __restrict__ up_f,
                           u16* __restrict__ weff_qkv, u16* __restrict__ weff_o) {
  int tid = blockIdx.x * blockDim.x + threadIdx.x;  // 4 * 1638400
  int w = tid / 1638400;
  int rem = tid - w * 1638400;
  int n = rem / 1280;
  int k = rem - n * 1280;
  const float* W = (w == 0) ? Wq : (w == 1) ? Wk : (w == 2) ? Wv : Wo;
  const float* up = up_f + w * 5120 + n * 4;
  const float* dn = down_f + w * 5120 + k;
  float v = W[rem] + up[0] * dn[0] + up[1] * dn[1280] + up[2] * dn[2560] + up[3] * dn[3840];
  u16 hv = f2bf(v);
  if (w < 3) weff_qkv[w * 1638400 + rem] = hv;
  else       weff_o[rem] = hv;
}

// ---------------------------------------------------------------------------
// Kernel 3: x fp32 -> bf16
// ---------------------------------------------------------------------------
__global__ void cvt_x(const float4* __restrict__ x, ushort4* __restrict__ xb) {
  int i = blockIdx.x * blockDim.x + threadIdx.x;  // 1310720
  float4 v = x[i];
  ushort4 o;
  o.x = f2bf(v.x); o.y = f2bf(v.y); o.z = f2bf(v.z); o.w = f2bf(v.w);
  xb[i] = o;
}

// ---------------------------------------------------------------------------
// QKV GEMM: C[M,N] = A[M,K] @ B[N,K]^T.  128x128 tile, BK=64.  Staged tiles
// use a rotate-by-row k-chunk swizzle (slot pos p of row r holds global chunk
// (p+r)&7) making BK=64 fragment reads conflict-free.  LDS 32 KB.
// ---------------------------------------------------------------------------
__global__ __launch_bounds__(256) void gemm128_qkv(const u16* __restrict__ A, const u16* __restrict__ Bm,
                                                   u16* __restrict__ qb, u16* __restrict__ kb,
                                                   u16* __restrict__ vbuf, int K) {
  __shared__ __align__(16) u16 lA[128 * 64];
  __shared__ __align__(16) u16 lB[128 * 64];
  const int t = threadIdx.x;
  const int lane = t & 63;
  const int l15 = lane & 15, quad = lane >> 4;
  const int wid = t >> 6;
  const int wm = (wid >> 1) * 64;
  const int wn = (wid & 1) * 64;
  const int bm = blockIdx.x * 128;
  const int bn = blockIdx.y * 128;
  floatx4 acc[4][4] = {};

  // Staging slot -> global offset (slot c: row=c>>3, pos=c&7, chunk=(pos+row)&7).
  int soff[4];
#pragma unroll
  for (int i = 0; i < 4; ++i) {
    int c = t + i * 256;
    int row = c >> 3, pos = c & 7;
    soff[i] = row * K + ((pos + row) & 7) * 8;
  }
  // Fragment read offsets (tile-invariant): row r, k-chunk kc8 at pos (kc8-r)&7.
  int afo[4][2], bfo[4][2];
#pragma unroll
  for (int i = 0; i < 4; ++i) {
#pragma unroll
    for (int ch = 0; ch < 2; ++ch) {
      int ra = wm + i * 16 + l15;
      int rb = wn + i * 16 + l15;
      int kc8 = ch * 4 + quad;
      afo[i][ch] = ra * 64 + ((kc8 - ra) & 7) * 8;
      bfo[i][ch] = rb * 64 + ((kc8 - rb) & 7) * 8;
    }
  }

  const u16* Ab = A + (long)bm * K;
  const u16* Bb = Bm + (long)bn * K;
  const int nkt = K >> 6;

  for (int kt = 0; kt < nkt; ++kt) {
    __syncthreads();
    const int k0 = kt * 64;
#pragma unroll
    for (int i = 0; i < 4; ++i) gll16(Ab + (long)soff[i] + k0, lA + (t + i * 256) * 8);
#pragma unroll
    for (int i = 0; i < 4; ++i) gll16(Bb + (long)soff[i] + k0, lB + (t + i * 256) * 8);
    __syncthreads();
#pragma unroll
    for (int ch = 0; ch < 2; ++ch) {
      bf16x8 af[4], bfr[4];
#pragma unroll
      for (int i = 0; i < 4; ++i) af[i] = *(const bf16x8*)(lA + afo[i][ch]);
#pragma unroll
      for (int i = 0; i < 4; ++i) bfr[i] = *(const bf16x8*)(lB + bfo[i][ch]);
#pragma unroll
      for (int i = 0; i < 4; ++i)
#pragma unroll
        for (int j = 0; j < 4; ++j)
          acc[i][j] = MFMA_BF16(af[i], bfr[j], acc[i][j]);
    }
  }

#pragma unroll
  for (int i = 0; i < 4; ++i) {
#pragma unroll
    for (int j = 0; j < 4; ++j) {
#pragma unroll
      for (int r = 0; r < 4; ++r) {
        int m = bm + wm + i * 16 + quad * 4 + r;
        int n = bn + wn + j * 16 + l15;
        u16 hv = f2bf(acc[i][j][r]);
        if (n < 1280) {
          qb[(long)m * 1280 + n] = hv;
        } else if (n < 2560) {
          kb[(long)m * 1280 + (n - 1280)] = hv;
        } else {
          vbuf[(long)m * 1280 + (n - 2560)] = hv;  // natural, coalesced
        }
      }
    }
  }
}

// ---------------------------------------------------------------------------
// V transpose (scalar, verified R10): vbuf[(b*2048+s)][n] ->
// vtb[(b*1280+n)*2048 + s].  64x64 tiles, tile stride 65.
// ---------------------------------------------------------------------------
__global__ __launch_bounds__(256) void vtrans(const u16* __restrict__ vbuf,
                                              u16* __restrict__ vtb) {
  __shared__ u16 tile[64 * 65];
  const int t = threadIdx.x;
  const int sb = blockIdx.x * 64, nb = blockIdx.y * 64, b = blockIdx.z;
  const u16* src = vbuf + ((long)(b * 2048 + sb)) * 1280 + nb;
#pragma unroll
  for (int it = 0; it < 16; ++it) {
    int idx = t + it * 256;
    int s = idx >> 6, n = idx & 63;
    tile[s * 65 + n] = src[(long)s * 1280 + n];
  }
  __syncthreads();
  u16* dst = vtb + ((long)(b * 1280 + nb)) * 2048 + sb;
#pragma unroll
  for (int it = 0; it < 16; ++it) {
    int idx = t + it * 256;
    int n = idx >> 6, s = idx & 63;
    dst[(long)n * 2048 + s] = tile[s * 65 + n];
  }
}

// ---------------------------------------------------------------------------
// O-proj GEMM: 64x128 tile, BK=64 (20 iters), swizzled staging as above.
// LDS 24 KB.  fp32 out + bias.
// ---------------------------------------------------------------------------
__global__ __launch_bounds__(256) void gemm64_o(const u16* __restrict__ A, const u16* __restrict__ Bm,
                                                float* __restrict__ outf,
                                                const float* __restrict__ bias, int K) {
  __shared__ __align__(16) u16 lA[64 * 64];
  __shared__ __align__(16) u16 lB[128 * 64];
  const int t = threadIdx.x;
  const int lane = t & 63;
  const int l15 = lane & 15, quad = lane >> 4;
  const int wid = t >> 6;
  const int bm = blockIdx.x * 64;
  const int bn = blockIdx.y * 128;
  floatx4 acc[4][2] = {};

  int aoff[2], boff[4];
#pragma unroll
  for (int i = 0; i < 2; ++i) {
    int c = t + i * 256;
    int row = c >> 3, pos = c & 7;
    aoff[i] = row * K + ((pos + row) & 7) * 8;
  }
#pragma unroll
  for (int i = 0; i < 4; ++i) {
    int c = t + i * 256;
    int row = c >> 3, pos = c & 7;
    boff[i] = row * K + ((pos + row) & 7) * 8;
  }
  int afo[4][2], bfo[2][2];
#pragma unroll
  for (int ch = 0; ch < 2; ++ch) {
    int kc8 = ch * 4 + quad;
#pragma unroll
    for (int i = 0; i < 4; ++i) {
      int ra = i * 16 + l15;
      afo[i][ch] = ra * 64 + ((kc8 - ra) & 7) * 8;
    }
#pragma unroll
    for (int j = 0; j < 2; ++j) {
      int rb = wid * 32 + j * 16 + l15;
      bfo[j][ch] = rb * 64 + ((kc8 - rb) & 7) * 8;
    }
  }

  const u16* Ab = A + (long)bm * K;
  const u16* Bb = Bm + (long)bn * K;
  const int nkt = K >> 6;

  for (int kt = 0; kt < nkt; ++kt) {
    __syncthreads();
    const int k0 = kt * 64;
#pragma unroll
    for (int i = 0; i < 2; ++i) gll16(Ab + (long)aoff[i] + k0, lA + (t + i * 256) * 8);
#pragma unroll
    for (int i = 0; i < 4; ++i) gll16(Bb + (long)boff[i] + k0, lB + (t + i * 256) * 8);
    __syncthreads();
#pragma unroll
    for (int ch = 0; ch < 2; ++ch) {
      bf16x8 af[4], bfr[2];
#pragma unroll
      for (int i = 0; i < 4; ++i) af[i] = *(const bf16x8*)(lA + afo[i][ch]);
#pragma unroll
      for (int j = 0; j < 2; ++j) bfr[j] = *(const bf16x8*)(lB + bfo[j][ch]);
#pragma unroll
      for (int i = 0; i < 4; ++i)
#pragma unroll
        for (int j = 0; j < 2; ++j)
          acc[i][j] = MFMA_BF16(af[i], bfr[j], acc[i][j]);
    }
  }

#pragma unroll
  for (int i = 0; i < 4; ++i) {
#pragma unroll
    for (int j = 0; j < 2; ++j) {
#pragma unroll
      for (int r = 0; r < 4; ++r) {
        int m = bm + i * 16 + quad * 4 + r;
        int n = bn + wid * 32 + j * 16 + l15;
        outf[(long)m * 1280 + n] = acc[i][j][r] + bias[n];
      }
    }
  }
}

// ---------------------------------------------------------------------------
// Flash attention v4: 8 warps, Q-block 128 rows (halves K/V staging per FLOP),
// full double-buffered K+V with counted vmcnt(5) + raw s_barrier so next
// tile's loads stay in flight across the barrier (T3/T4).  Combined KV LDS
// region per buffer: K (rotated, 10240 u16) then V (XOR-swizzled, 10240 u16);
// staging dest is linear base + c*8 for chunk c = t + i*512.  LDS 99 KB ->
// 1 block/CU, 8 waves (same 2 waves/SIMD as v3 but no per-tile vmcnt(0)
// drain and half the staging traffic).
// ---------------------------------------------------------------------------
__global__ __launch_bounds__(512) void flash_attn(const u16* __restrict__ qb,
                                                  const u16* __restrict__ kb,
                                                  const u16* __restrict__ vtb,
                                                  u16* __restrict__ attn) {
  const int S = 2048, D = 1280, HD = 160;
  __shared__ __align__(16) u16 kv_lds[2][64 * 160 + 160 * 64];
  __shared__ __align__(16) u16 p_lds[8][16 * 76];
  const int t = threadIdx.x, lane = t & 63, wid = t >> 6;
  const int quad = lane >> 4, l15 = lane & 15;
  const int bh = blockIdx.y, b = bh >> 3, h = bh & 7;
  const int q0 = blockIdx.x * 128 + wid * 16;
  const float kS = 0.11404582025f;

  bf16x8 aq[5];
  {
    const u16* qg = qb + ((long)(b * 2048 + q0 + l15)) * D + h * HD + quad * 8;
#pragma unroll
    for (int dc = 0; dc < 5; ++dc) aq[dc] = *(const bf16x8*)(qg + dc * 32);
  }

  // Staging sources: 2560 16B-chunks/tile.  c<1280: K chunk (key=c/20, rotated
  // col (pos-key)%20).  c>=1280: V chunk (row=(c-1280)>>3, col swz^(row&7)).
  const u16* sg[5];
  int sadv[5];
#pragma unroll
  for (int i = 0; i < 5; ++i) {
    int c = t + i * 512;
    if (c < 1280) {
      int key = c / 20, pos = c - key * 20;
      int ccol = pos - (key % 20);
      if (ccol < 0) ccol += 20;
      sg[i] = kb + ((long)(b * 2048 + key)) * D + h * HD + ccol * 8;
      sadv[i] = 64 * D;
    } else {
      int c2 = c - 1280;
      int vrow = c2 >> 3, swz = c2 & 7;
      int vcol = swz ^ (vrow & 7);
      sg[i] = vtb + ((long)(b * 1280 + h * HD + vrow)) * 2048 + vcol * 8;
      sadv[i] = 64;
    }
  }

  // Fragment read offsets (u16 units into a KV buffer).
  int kfo[4][5];
#pragma unroll
  for (int j = 0; j < 4; ++j) {
    int key = j * 16 + l15;
    int r0 = (quad + key) % 20;
#pragma unroll
    for (int dc = 0; dc < 5; ++dc) {
      int rot = r0 + dc * 4;
      if (rot >= 20) rot -= 20;
      kfo[j][dc] = (key * 20 + rot) * 8;
    }
  }
  int vfo[10][2];
#pragma unroll
  for (int dc = 0; dc < 10; ++dc) {
    int row = dc * 16 + l15;
#pragma unroll
    for (int ks = 0; ks < 2; ++ks) {
      int sw = (ks * 4 + quad) ^ (row & 7);
      vfo[dc][ks] = 10240 + (row * 8 + sw) * 8;
    }
  }

  float l_part[4] = {0.f, 0.f, 0.f, 0.f};
  floatx4 o_acc[10] = {};

  // Prologue: stage tile 0 into buffer 0.
#pragma unroll
  for (int i = 0; i < 5; ++i) {
    gll16(sg[i], &kv_lds[0][0] + (t + i * 512) * 8);
    sg[i] += sadv[i];
  }

  for (int kt0 = 0; kt0 < 32; ++kt0) {
    u16* cbase = &kv_lds[kt0 & 1][0];
    if (kt0 < 31) {
      u16* nbase = &kv_lds[(kt0 & 1) ^ 1][0];
#pragma unroll
      for (int i = 0; i < 5; ++i) {
        gll16(sg[i], nbase + (t + i * 512) * 8);
        sg[i] += sadv[i];
      }
      asm volatile("s_waitcnt vmcnt(5)" ::: "memory");
    } else {
      asm volatile("s_waitcnt vmcnt(0)" ::: "memory");
    }
    __builtin_amdgcn_s_barrier();
    __builtin_amdgcn_sched_barrier(0);

    floatx4 s[4] = {};
#pragma unroll
    for (int dc = 0; dc < 5; ++dc) {
#pragma unroll
      for (int j = 0; j < 4; ++j) {
        bf16x8 kf = *(const bf16x8*)(cbase + kfo[j][dc]);
        s[j] = MFMA_BF16(aq[dc], kf, s[j]);
      }
    }

#pragma unroll
    for (int r = 0; r < 4; ++r) {
      float p0 = __builtin_exp2f(fminf(s[0][r] * kS, 80.f));
      float p1 = __builtin_exp2f(fminf(s[1][r] * kS, 80.f));
      float p2 = __builtin_exp2f(fminf(s[2][r] * kS, 80.f));
      float p3 = __builtin_exp2f(fminf(s[3][r] * kS, 80.f));
      l_part[r] += (p0 + p1) + (p2 + p3);
      u16* pw = p_lds[wid] + (quad * 4 + r) * 76 + l15;
      pw[0]  = f2bf(p0);
      pw[16] = f2bf(p1);
      pw[32] = f2bf(p2);
      pw[48] = f2bf(p3);
    }
    asm volatile("s_waitcnt lgkmcnt(0)" ::: "memory");

    bf16x8 paA = *(const bf16x8*)(p_lds[wid] + l15 * 76 + quad * 8);
    bf16x8 paB = *(const bf16x8*)(p_lds[wid] + l15 * 76 + 32 + quad * 8);
#pragma unroll
    for (int dc = 0; dc < 10; ++dc) {
      bf16x8 vfA = *(const bf16x8*)(cbase + vfo[dc][0]);
      bf16x8 vfB = *(const bf16x8*)(cbase + vfo[dc][1]);
      o_acc[dc] = MFMA_BF16(paA, vfA, o_acc[dc]);
      o_acc[dc] = MFMA_BF16(paB, vfB, o_acc[dc]);
    }
    __builtin_amdgcn_sched_barrier(0);
    __builtin_amdgcn_s_barrier();
  }

  float rl[4];
#pragma unroll
  for (int r = 0; r < 4; ++r) {
    float rs = l_part[r];
    rs += __shfl_xor(rs, 1, 64);
    rs += __shfl_xor(rs, 2, 64);
    rs += __shfl_xor(rs, 4, 64);
    rs += __shfl_xor(rs, 8, 64);
    rl[r] = 1.0f / rs;
  }
#pragma unroll
  for (int dc = 0; dc < 10; ++dc) {
#pragma unroll
    for (int r = 0; r < 4; ++r) {
      float v = o_acc[dc][r] * rl[r];
      int row = q0 + quad * 4 + r;
      int col = h * HD + dc * 16 + l15;
      attn[((long)(b * 2048 + row)) * D + col] = f2bf(v);
    }
  }
}

// ---------------------------------------------------------------------------
// Launcher.  Workspace (~76.2 MB):
//   xb @0 | weff_qkv @10485760 | weff_o @20316160 | qbuf @23592960
//   kbuf @34078720 | vtb @44564480 | attn @55050240 | down_f @65536000
//   up_f @65617920 | vbuf @65699840 (10485760)
// ---------------------------------------------------------------------------
extern "C" void kernel_launch(void* const* d_in, const int* in_sizes, int n_in,
                              void* d_out, int out_size, void* d_ws, size_t ws_size,
                              hipStream_t stream) {
  const float* x   = (const float*)d_in[0];
  const float* pal = (const float*)d_in[1];
  const float* Wq  = (const float*)d_in[2];
  const float* Wk  = (const float*)d_in[3];
  const float* Wv  = (const float*)d_in[4];
  const float* Wo  = (const float*)d_in[5];
  const float* bo  = (const float*)d_in[6];
  const float* qd  = (const float*)d_in[7];
  const float* qu  = (const float*)d_in[8];
  const float* kd  = (const float*)d_in[9];
  const float* ku  = (const float*)d_in[10];
  const float* vd  = (const float*)d_in[11];
  const float* vu  = (const float*)d_in[12];
  const float* od  = (const float*)d_in[13];
  const float* ou  = (const float*)d_in[14];
  float* out = (float*)d_out;

  char* ws = (char*)d_ws;
  u16* xb       = (u16*)(ws);
  u16* weff_qkv = (u16*)(ws + 10485760);
  u16* weff_o   = (u16*)(ws + 20316160);
  u16* qbuf     = (u16*)(ws + 23592960);
  u16* kbuf     = (u16*)(ws + 34078720);
  u16* vtb      = (u16*)(ws + 44564480);
  u16* attn     = (u16*)(ws + 55050240);
  float* down_f = (float*)(ws + 65536000);
  float* up_f   = (float*)(ws + 65617920);
  u16* vbuf     = (u16*)(ws + 65699840);

  prep_downup<<<160, 256, 0, stream>>>(pal, qd, qu, kd, ku, vd, vu, od, ou, down_f, up_f);
  build_weff<<<25600, 256, 0, stream>>>(Wq, Wk, Wv, Wo, down_f, up_f, weff_qkv, weff_o);
  cvt_x<<<5120, 256, 0, stream>>>((const float4*)x, (ushort4*)xb);
  gemm128_qkv<<<dim3(32, 30), 256, 0, stream>>>(xb, weff_qkv, qbuf, kbuf, vbuf, 1280);
  vtrans<<<dim3(32, 20, 2), 256, 0, stream>>>(vbuf, vtb);
  flash_attn<<<dim3(16, 16), 512, 0, stream>>>(qbuf, kbuf, vtb, attn);
  gemm64_o<<<dim3(64, 10), 256, 0, stream>>>(attn, weff_o, out, bo, 1280);
}

// Round 2
// 284.602 us; speedup vs baseline: 1.0673x; 1.0673x over previous
//
#include <hip/hip_runtime.h>

typedef unsigned short u16;
typedef unsigned int u32;
typedef __attribute__((ext_vector_type(4))) float floatx4;
typedef __attribute__((ext_vector_type(16))) float floatx16;
typedef __attribute__((ext_vector_type(8))) __bf16 bf16x8;

#define MFMA_BF16(a, b, c) __builtin_amdgcn_mfma_f32_16x16x32_bf16((a), (b), (c), 0, 0, 0)
#define MFMA32(a, b, c) __builtin_amdgcn_mfma_f32_32x32x16_bf16((a), (b), (c), 0, 0, 0)

typedef const __attribute__((address_space(1))) void* gas_ptr;
typedef __attribute__((address_space(3))) void* las_ptr;

__device__ __forceinline__ void gll16(const void* g, void* l) {
  __builtin_amdgcn_global_load_lds((gas_ptr)g, (las_ptr)l, 16, 0, 0);
}

__device__ __forceinline__ u16 f2bf(float x) {
  u32 u = __builtin_bit_cast(u32, x);
  u = (u + 0x7fffu + ((u >> 16) & 1u)) >> 16;
  return (u16)u;
}

// ---------------------------------------------------------------------------
// Kernel 1: down/up vectors from palette.
// ---------------------------------------------------------------------------
__global__ void prep_downup(const float* __restrict__ pal,
                            const float* __restrict__ qd, const float* __restrict__ qu,
                            const float* __restrict__ kd, const float* __restrict__ ku,
                            const float* __restrict__ vd, const float* __restrict__ vu,
                            const float* __restrict__ od, const float* __restrict__ ou,
                            float* __restrict__ down_f, float* __restrict__ up_f) {
  int tid = blockIdx.x * blockDim.x + threadIdx.x;
  int w = tid / 10240;
  int rem = tid - w * 10240;
  const float* dsrc = (w == 0) ? qd : (w == 1) ? kd : (w == 2) ? vd : od;
  const float* usrc = (w == 0) ? qu : (w == 1) ? ku : (w == 2) ? vu : ou;
  bool isdown = rem < 5120;
  int row = isdown ? rem : rem - 5120;
  const float* src = (isdown ? dsrc : usrc) + row * 15;
  float s = 0.f;
#pragma unroll
  for (int p = 0; p < 15; ++p) s += pal[p] * src[p];
  if (isdown) down_f[w * 5120 + row] = s;
  else        up_f[w * 5120 + row] = s;
}

// ---------------------------------------------------------------------------
// Kernel 2: W_eff[n][k] = W[n][k] + sum_r up[n][r]*down[r][k], cast to bf16.
// ---------------------------------------------------------------------------
__global__ void build_weff(const float* __restrict__ Wq, const float* __restrict__ Wk,
                           const float* __restrict__ Wv, const float* __restrict__ Wo,
                           const float* __restrict__ down_f, const float* __restrict__ up_f,
                           u16* __restrict__ weff_qkv, u16* __restrict__ weff_o) {
  int tid = blockIdx.x * blockDim.x + threadIdx.x;  // 4 * 1638400
  int w = tid / 1638400;
  int rem = tid - w * 1638400;
  int n = rem / 1280;
  int k = rem - n * 1280;
  const float* W = (w == 0) ? Wq : (w == 1) ? Wk : (w == 2) ? Wv : Wo;
  const float* up = up_f + w * 5120 + n * 4;
  const float* dn = down_f + w * 5120 + k;
  float v = W[rem] + up[0] * dn[0] + up[1] * dn[1280] + up[2] * dn[2560] + up[3] * dn[3840];
  u16 hv = f2bf(v);
  if (w < 3) weff_qkv[w * 1638400 + rem] = hv;
  else       weff_o[rem] = hv;
}

// ---------------------------------------------------------------------------
// Kernel 3: x fp32 -> bf16
// ---------------------------------------------------------------------------
__global__ void cvt_x(const float4* __restrict__ x, ushort4* __restrict__ xb) {
  int i = blockIdx.x * blockDim.x + threadIdx.x;  // 1310720
  float4 v = x[i];
  ushort4 o;
  o.x = f2bf(v.x); o.y = f2bf(v.y); o.z = f2bf(v.z); o.w = f2bf(v.w);
  xb[i] = o;
}

// ---------------------------------------------------------------------------
// QKV GEMM: C[M,N] = A[M,K] @ B[N,K]^T.  128x128 tile, BK=64.  Staged tiles
// use a rotate-by-row k-chunk swizzle (slot pos p of row r holds global chunk
// (p+r)&7) making BK=64 fragment reads conflict-free.  LDS 32 KB.
// ---------------------------------------------------------------------------
__global__ __launch_bounds__(256) void gemm128_qkv(const u16* __restrict__ A, const u16* __restrict__ Bm,
                                                   u16* __restrict__ qb, u16* __restrict__ kb,
                                                   u16* __restrict__ vbuf, int K) {
  __shared__ __align__(16) u16 lA[128 * 64];
  __shared__ __align__(16) u16 lB[128 * 64];
  const int t = threadIdx.x;
  const int lane = t & 63;
  const int l15 = lane & 15, quad = lane >> 4;
  const int wid = t >> 6;
  const int wm = (wid >> 1) * 64;
  const int wn = (wid & 1) * 64;
  const int bm = blockIdx.x * 128;
  const int bn = blockIdx.y * 128;
  floatx4 acc[4][4] = {};

  // Staging slot -> global offset (slot c: row=c>>3, pos=c&7, chunk=(pos+row)&7).
  int soff[4];
#pragma unroll
  for (int i = 0; i < 4; ++i) {
    int c = t + i * 256;
    int row = c >> 3, pos = c & 7;
    soff[i] = row * K + ((pos + row) & 7) * 8;
  }
  // Fragment read offsets (tile-invariant): row r, k-chunk kc8 at pos (kc8-r)&7.
  int afo[4][2], bfo[4][2];
#pragma unroll
  for (int i = 0; i < 4; ++i) {
#pragma unroll
    for (int ch = 0; ch < 2; ++ch) {
      int ra = wm + i * 16 + l15;
      int rb = wn + i * 16 + l15;
      int kc8 = ch * 4 + quad;
      afo[i][ch] = ra * 64 + ((kc8 - ra) & 7) * 8;
      bfo[i][ch] = rb * 64 + ((kc8 - rb) & 7) * 8;
    }
  }

  const u16* Ab = A + (long)bm * K;
  const u16* Bb = Bm + (long)bn * K;
  const int nkt = K >> 6;

  for (int kt = 0; kt < nkt; ++kt) {
    __syncthreads();
    const int k0 = kt * 64;
#pragma unroll
    for (int i = 0; i < 4; ++i) gll16(Ab + (long)soff[i] + k0, lA + (t + i * 256) * 8);
#pragma unroll
    for (int i = 0; i < 4; ++i) gll16(Bb + (long)soff[i] + k0, lB + (t + i * 256) * 8);
    __syncthreads();
#pragma unroll
    for (int ch = 0; ch < 2; ++ch) {
      bf16x8 af[4], bfr[4];
#pragma unroll
      for (int i = 0; i < 4; ++i) af[i] = *(const bf16x8*)(lA + afo[i][ch]);
#pragma unroll
      for (int i = 0; i < 4; ++i) bfr[i] = *(const bf16x8*)(lB + bfo[i][ch]);
#pragma unroll
      for (int i = 0; i < 4; ++i)
#pragma unroll
        for (int j = 0; j < 4; ++j)
          acc[i][j] = MFMA_BF16(af[i], bfr[j], acc[i][j]);
    }
  }

#pragma unroll
  for (int i = 0; i < 4; ++i) {
#pragma unroll
    for (int j = 0; j < 4; ++j) {
#pragma unroll
      for (int r = 0; r < 4; ++r) {
        int m = bm + wm + i * 16 + quad * 4 + r;
        int n = bn + wn + j * 16 + l15;
        u16 hv = f2bf(acc[i][j][r]);
        if (n < 1280) {
          qb[(long)m * 1280 + n] = hv;
        } else if (n < 2560) {
          kb[(long)m * 1280 + (n - 1280)] = hv;
        } else {
          vbuf[(long)m * 1280 + (n - 2560)] = hv;  // natural, coalesced
        }
      }
    }
  }
}

// ---------------------------------------------------------------------------
// V transpose (scalar, verified R10): vbuf[(b*2048+s)][n] ->
// vtb[(b*1280+n)*2048 + s].  64x64 tiles, tile stride 65.
// ---------------------------------------------------------------------------
__global__ __launch_bounds__(256) void vtrans(const u16* __restrict__ vbuf,
                                              u16* __restrict__ vtb) {
  __shared__ u16 tile[64 * 65];
  const int t = threadIdx.x;
  const int sb = blockIdx.x * 64, nb = blockIdx.y * 64, b = blockIdx.z;
  const u16* src = vbuf + ((long)(b * 2048 + sb)) * 1280 + nb;
#pragma unroll
  for (int it = 0; it < 16; ++it) {
    int idx = t + it * 256;
    int s = idx >> 6, n = idx & 63;
    tile[s * 65 + n] = src[(long)s * 1280 + n];
  }
  __syncthreads();
  u16* dst = vtb + ((long)(b * 1280 + nb)) * 2048 + sb;
#pragma unroll
  for (int it = 0; it < 16; ++it) {
    int idx = t + it * 256;
    int n = idx >> 6, s = idx & 63;
    dst[(long)n * 2048 + s] = tile[s * 65 + n];
  }
}

// ---------------------------------------------------------------------------
// O-proj GEMM: 64x128 tile, BK=64 (20 iters), swizzled staging as above.
// LDS 24 KB.  fp32 out + bias.
// ---------------------------------------------------------------------------
__global__ __launch_bounds__(256) void gemm64_o(const u16* __restrict__ A, const u16* __restrict__ Bm,
                                                float* __restrict__ outf,
                                                const float* __restrict__ bias, int K) {
  __shared__ __align__(16) u16 lA[64 * 64];
  __shared__ __align__(16) u16 lB[128 * 64];
  const int t = threadIdx.x;
  const int lane = t & 63;
  const int l15 = lane & 15, quad = lane >> 4;
  const int wid = t >> 6;
  const int bm = blockIdx.x * 64;
  const int bn = blockIdx.y * 128;
  floatx4 acc[4][2] = {};

  int aoff[2], boff[4];
#pragma unroll
  for (int i = 0; i < 2; ++i) {
    int c = t + i * 256;
    int row = c >> 3, pos = c & 7;
    aoff[i] = row * K + ((pos + row) & 7) * 8;
  }
#pragma unroll
  for (int i = 0; i < 4; ++i) {
    int c = t + i * 256;
    int row = c >> 3, pos = c & 7;
    boff[i] = row * K + ((pos + row) & 7) * 8;
  }
  int afo[4][2], bfo[2][2];
#pragma unroll
  for (int ch = 0; ch < 2; ++ch) {
    int kc8 = ch * 4 + quad;
#pragma unroll
    for (int i = 0; i < 4; ++i) {
      int ra = i * 16 + l15;
      afo[i][ch] = ra * 64 + ((kc8 - ra) & 7) * 8;
    }
#pragma unroll
    for (int j = 0; j < 2; ++j) {
      int rb = wid * 32 + j * 16 + l15;
      bfo[j][ch] = rb * 64 + ((kc8 - rb) & 7) * 8;
    }
  }

  const u16* Ab = A + (long)bm * K;
  const u16* Bb = Bm + (long)bn * K;
  const int nkt = K >> 6;

  for (int kt = 0; kt < nkt; ++kt) {
    __syncthreads();
    const int k0 = kt * 64;
#pragma unroll
    for (int i = 0; i < 2; ++i) gll16(Ab + (long)aoff[i] + k0, lA + (t + i * 256) * 8);
#pragma unroll
    for (int i = 0; i < 4; ++i) gll16(Bb + (long)boff[i] + k0, lB + (t + i * 256) * 8);
    __syncthreads();
#pragma unroll
    for (int ch = 0; ch < 2; ++ch) {
      bf16x8 af[4], bfr[2];
#pragma unroll
      for (int i = 0; i < 4; ++i) af[i] = *(const bf16x8*)(lA + afo[i][ch]);
#pragma unroll
      for (int j = 0; j < 2; ++j) bfr[j] = *(const bf16x8*)(lB + bfo[j][ch]);
#pragma unroll
      for (int i = 0; i < 4; ++i)
#pragma unroll
        for (int j = 0; j < 2; ++j)
          acc[i][j] = MFMA_BF16(af[i], bfr[j], acc[i][j]);
    }
  }

#pragma unroll
  for (int i = 0; i < 4; ++i) {
#pragma unroll
    for (int j = 0; j < 2; ++j) {
#pragma unroll
      for (int r = 0; r < 4; ++r) {
        int m = bm + i * 16 + quad * 4 + r;
        int n = bn + wid * 32 + j * 16 + l15;
        outf[(long)m * 1280 + n] = acc[i][j][r] + bias[n];
      }
    }
  }
}

// ---------------------------------------------------------------------------
// Flash attention v5: LDS-BW attack.  32x32x16 MFMA doubles FLOP per LDS byte
// (1 KB fragment -> 32K FLOP vs 16K).  8 waves = 4 row-groups (32 Q-rows) x
// 2 key-halves (32 keys).  Per-wave QK: 10 MFMA (2 chains of 5); softmax in
// C-layout regs; P -> 2 KB/wave XOR-swizzled LDS -> 2 A-frags; PV: 10 MFMA.
// Key-half partial O (80 f32) + l (16 f32) pair-reduced once at end via
// reused kv_lds/p_lds.  Staging/double-buffer/vmcnt(5) identical to v4.
// LDS 96 KB.
// ---------------------------------------------------------------------------
__global__ __launch_bounds__(512) void flash_attn(const u16* __restrict__ qb,
                                                  const u16* __restrict__ kb,
                                                  const u16* __restrict__ vtb,
                                                  u16* __restrict__ attn) {
  const int D = 1280, HD = 160;
  __shared__ __align__(16) u16 kv_lds[2][20480];  // K 10240 | V 10240 per buf
  __shared__ __align__(16) u16 p_lds[8][1024];    // 2 KB per wave
  const int t = threadIdx.x, lane = t & 63, wid = t >> 6;
  const int l31 = lane & 31, hi = lane >> 5;
  const int rg = wid >> 1, kh = wid & 1;
  const int bh = blockIdx.y, b = bh >> 3, h = bh & 7;
  const int q0 = blockIdx.x * 128 + rg * 32;
  const float kS = 0.11404582025f;

  // Q fragments: row q0+l31, d = kw*16 + hi*8 (+idx).
  bf16x8 aq[10];
  {
    const u16* qg = qb + ((long)(b * 2048 + q0 + l31)) * D + h * HD + hi * 8;
#pragma unroll
    for (int kw = 0; kw < 10; ++kw) aq[kw] = *(const bf16x8*)(qg + kw * 16);
  }

  // Staging sources (identical to v4): 2560 16B-chunks/tile.
  const u16* sg[5];
  int sadv[5];
#pragma unroll
  for (int i = 0; i < 5; ++i) {
    int c = t + i * 512;
    if (c < 1280) {
      int key = c / 20, pos = c - key * 20;
      int ccol = pos - (key % 20);
      if (ccol < 0) ccol += 20;
      sg[i] = kb + ((long)(b * 2048 + key)) * D + h * HD + ccol * 8;
      sadv[i] = 64 * D;
    } else {
      int c2 = c - 1280;
      int vrow = c2 >> 3, swz = c2 & 7;
      int vcol = swz ^ (vrow & 7);
      sg[i] = vtb + ((long)(b * 1280 + h * HD + vrow)) * 2048 + vcol * 8;
      sadv[i] = 64;
    }
  }

  // K fragment offsets (u16): key = kh*32+l31; global d-chunk g = kw*2+hi
  // stored at pos (g+key)%20.
  int kfo[10];
  {
    int key = kh * 32 + l31;
#pragma unroll
    for (int kw = 0; kw < 10; ++kw) {
      int g = kw * 2 + hi;
      int pos = (g + key) % 20;
      kfo[kw] = (key * 20 + pos) * 8;
    }
  }
  // V fragment offsets: d-row = db*32+l31; global key-chunk gc = kh*4+kwv*2+hi
  // stored at swz = gc ^ (d&7).
  int vfo[5][2];
#pragma unroll
  for (int db = 0; db < 5; ++db) {
#pragma unroll
    for (int kwv = 0; kwv < 2; ++kwv) {
      int d = db * 32 + l31;
      int gc = kh * 4 + kwv * 2 + hi;
      int sw = gc ^ (d & 7);
      vfo[db][kwv] = 10240 + (d * 8 + sw) * 8;
    }
  }
  // P A-frag byte offsets in wave's p_lds: row l31, chunk (ks*2+hi)^(l31&3).
  int pfo[2];
#pragma unroll
  for (int ks = 0; ks < 2; ++ks)
    pfo[ks] = l31 * 64 + (((ks * 2 + hi) ^ (l31 & 3)) << 4);

  float l_acc[16] = {};
  floatx16 o_acc[5] = {};

  // Prologue: stage tile 0 into buffer 0.
#pragma unroll
  for (int i = 0; i < 5; ++i) {
    gll16(sg[i], &kv_lds[0][0] + (t + i * 512) * 8);
    sg[i] += sadv[i];
  }

  for (int kt0 = 0; kt0 < 32; ++kt0) {
    u16* cbase = &kv_lds[kt0 & 1][0];
    if (kt0 < 31) {
      u16* nbase = &kv_lds[(kt0 & 1) ^ 1][0];
#pragma unroll
      for (int i = 0; i < 5; ++i) {
        gll16(sg[i], nbase + (t + i * 512) * 8);
        sg[i] += sadv[i];
      }
      asm volatile("s_waitcnt vmcnt(5)" ::: "memory");
    } else {
      asm volatile("s_waitcnt vmcnt(0)" ::: "memory");
    }
    __builtin_amdgcn_s_barrier();
    __builtin_amdgcn_sched_barrier(0);

    // QK: two 5-deep chains over even/odd d-windows.
    floatx16 s0 = {}, s1 = {};
#pragma unroll
    for (int kw = 0; kw < 5; ++kw) {
      bf16x8 k0 = *(const bf16x8*)(cbase + kfo[kw * 2]);
      bf16x8 k1 = *(const bf16x8*)(cbase + kfo[kw * 2 + 1]);
      s0 = MFMA32(aq[kw * 2], k0, s0);
      s1 = MFMA32(aq[kw * 2 + 1], k1, s1);
    }

    // Softmax in C-layout regs; write P bf16 to wave-local swizzled LDS.
    u16* pw = p_lds[wid];
#pragma unroll
    for (int r = 0; r < 16; ++r) {
      float sv = (s0[r] + s1[r]) * kS;
      float p = __builtin_exp2f(fminf(sv, 80.f));
      l_acc[r] += p;
      int qr = (r & 3) + 8 * (r >> 2) + 4 * hi;
      int boff = qr * 64 + (((l31 >> 3) ^ (r & 3)) << 4) + (l31 & 7) * 2;
      *(u16*)((char*)pw + boff) = f2bf(p);
    }
    asm volatile("s_waitcnt lgkmcnt(0)" ::: "memory");
    __builtin_amdgcn_sched_barrier(0);

    bf16x8 pa0 = *(const bf16x8*)((const char*)pw + pfo[0]);
    bf16x8 pa1 = *(const bf16x8*)((const char*)pw + pfo[1]);
#pragma unroll
    for (int db = 0; db < 5; ++db) {
      bf16x8 v0 = *(const bf16x8*)(cbase + vfo[db][0]);
      bf16x8 v1 = *(const bf16x8*)(cbase + vfo[db][1]);
      o_acc[db] = MFMA32(pa0, v0, o_acc[db]);
      o_acc[db] = MFMA32(pa1, v1, o_acc[db]);
    }
    __builtin_amdgcn_sched_barrier(0);
    __builtin_amdgcn_s_barrier();
  }

  // Epilogue: pair-reduce key halves.  kh=1 dumps partials into reused LDS.
  float* oscr = (float*)&kv_lds[0][0];   // 20480 f32: rg*5120 + (db*16+r)*64 + lane
  float* lscr = (float*)&p_lds[0][0];    // 4096 f32:  rg*1024 + r*64 + lane
  if (kh == 1) {
#pragma unroll
    for (int db = 0; db < 5; ++db)
#pragma unroll
      for (int r = 0; r < 16; ++r)
        oscr[rg * 5120 + (db * 16 + r) * 64 + lane] = o_acc[db][r];
#pragma unroll
    for (int r = 0; r < 16; ++r)
      lscr[rg * 1024 + r * 64 + lane] = l_acc[r];
  }
  __syncthreads();
  if (kh == 0) {
    float rl[16];
#pragma unroll
    for (int r = 0; r < 16; ++r) {
      float rs = l_acc[r] + lscr[rg * 1024 + r * 64 + lane];
      rs += __shfl_xor(rs, 1, 64);
      rs += __shfl_xor(rs, 2, 64);
      rs += __shfl_xor(rs, 4, 64);
      rs += __shfl_xor(rs, 8, 64);
      rs += __shfl_xor(rs, 16, 64);
      rl[r] = 1.0f / rs;
    }
#pragma unroll
    for (int db = 0; db < 5; ++db) {
#pragma unroll
      for (int r = 0; r < 16; ++r) {
        float v = (o_acc[db][r] + oscr[rg * 5120 + (db * 16 + r) * 64 + lane]) * rl[r];
        int row = q0 + (r & 3) + 8 * (r >> 2) + 4 * hi;
        int col = h * HD + db * 32 + l31;
        attn[((long)(b * 2048 + row)) * D + col] = f2bf(v);
      }
    }
  }
}

// ---------------------------------------------------------------------------
// Launcher.  Workspace (~76.2 MB):
//   xb @0 | weff_qkv @10485760 | weff_o @20316160 | qbuf @23592960
//   kbuf @34078720 | vtb @44564480 | attn @55050240 | down_f @65536000
//   up_f @65617920 | vbuf @65699840 (10485760)
// ---------------------------------------------------------------------------
extern "C" void kernel_launch(void* const* d_in, const int* in_sizes, int n_in,
                              void* d_out, int out_size, void* d_ws, size_t ws_size,
                              hipStream_t stream) {
  const float* x   = (const float*)d_in[0];
  const float* pal = (const float*)d_in[1];
  const float* Wq  = (const float*)d_in[2];
  const float* Wk  = (const float*)d_in[3];
  const float* Wv  = (const float*)d_in[4];
  const float* Wo  = (const float*)d_in[5];
  const float* bo  = (const float*)d_in[6];
  const float* qd  = (const float*)d_in[7];
  const float* qu  = (const float*)d_in[8];
  const float* kd  = (const float*)d_in[9];
  const float* ku  = (const float*)d_in[10];
  const float* vd  = (const float*)d_in[11];
  const float* vu  = (const float*)d_in[12];
  const float* od  = (const float*)d_in[13];
  const float* ou  = (const float*)d_in[14];
  float* out = (float*)d_out;

  char* ws = (char*)d_ws;
  u16* xb       = (u16*)(ws);
  u16* weff_qkv = (u16*)(ws + 10485760);
  u16* weff_o   = (u16*)(ws + 20316160);
  u16* qbuf     = (u16*)(ws + 23592960);
  u16* kbuf     = (u16*)(ws + 34078720);
  u16* vtb      = (u16*)(ws + 44564480);
  u16* attn     = (u16*)(ws + 55050240);
  float* down_f = (float*)(ws + 65536000);
  float* up_f   = (float*)(ws + 65617920);
  u16* vbuf     = (u16*)(ws + 65699840);

  prep_downup<<<160, 256, 0, stream>>>(pal, qd, qu, kd, ku, vd, vu, od, ou, down_f, up_f);
  build_weff<<<25600, 256, 0, stream>>>(Wq, Wk, Wv, Wo, down_f, up_f, weff_qkv, weff_o);
  cvt_x<<<5120, 256, 0, stream>>>((const float4*)x, (ushort4*)xb);
  gemm128_qkv<<<dim3(32, 30), 256, 0, stream>>>(xb, weff_qkv, qbuf, kbuf, vbuf, 1280);
  vtrans<<<dim3(32, 20, 2), 256, 0, stream>>>(vbuf, vtb);
  flash_attn<<<dim3(16, 16), 512, 0, stream>>>(qbuf, kbuf, vtb, attn);
  gemm64_o<<<dim3(64, 10), 256, 0, stream>>>(attn, weff_o, out, bo, 1280);
}

// Round 3
// 269.342 us; speedup vs baseline: 1.1277x; 1.0567x over previous
//
#include <hip/hip_runtime.h>

typedef unsigned short u16;
typedef unsigned int u32;
typedef __attribute__((ext_vector_type(4))) float floatx4;
typedef __attribute__((ext_vector_type(16))) float floatx16;
typedef __attribute__((ext_vector_type(8))) __bf16 bf16x8;
typedef __attribute__((ext_vector_type(2))) unsigned int u32x2;
typedef __attribute__((ext_vector_type(4))) unsigned int u32x4;

#define MFMA_BF16(a, b, c) __builtin_amdgcn_mfma_f32_16x16x32_bf16((a), (b), (c), 0, 0, 0)
#define MFMA32(a, b, c) __builtin_amdgcn_mfma_f32_32x32x16_bf16((a), (b), (c), 0, 0, 0)

typedef const __attribute__((address_space(1))) void* gas_ptr;
typedef __attribute__((address_space(3))) void* las_ptr;

__device__ __forceinline__ void gll16(const void* g, void* l) {
  __builtin_amdgcn_global_load_lds((gas_ptr)g, (las_ptr)l, 16, 0, 0);
}

__device__ __forceinline__ u16 f2bf(float x) {
  u32 u = __builtin_bit_cast(u32, x);
  u = (u + 0x7fffu + ((u >> 16) & 1u)) >> 16;
  return (u16)u;
}

__device__ __forceinline__ u32 cvtpk(float lo, float hi) {
  u32 r;
  asm("v_cvt_pk_bf16_f32 %0, %1, %2" : "=v"(r) : "v"(lo), "v"(hi));
  return r;
}

// ---------------------------------------------------------------------------
// Kernel 1: down/up vectors from palette.
// ---------------------------------------------------------------------------
__global__ void prep_downup(const float* __restrict__ pal,
                            const float* __restrict__ qd, const float* __restrict__ qu,
                            const float* __restrict__ kd, const float* __restrict__ ku,
                            const float* __restrict__ vd, const float* __restrict__ vu,
                            const float* __restrict__ od, const float* __restrict__ ou,
                            float* __restrict__ down_f, float* __restrict__ up_f) {
  int tid = blockIdx.x * blockDim.x + threadIdx.x;
  int w = tid / 10240;
  int rem = tid - w * 10240;
  const float* dsrc = (w == 0) ? qd : (w == 1) ? kd : (w == 2) ? vd : od;
  const float* usrc = (w == 0) ? qu : (w == 1) ? ku : (w == 2) ? vu : ou;
  bool isdown = rem < 5120;
  int row = isdown ? rem : rem - 5120;
  const float* src = (isdown ? dsrc : usrc) + row * 15;
  float s = 0.f;
#pragma unroll
  for (int p = 0; p < 15; ++p) s += pal[p] * src[p];
  if (isdown) down_f[w * 5120 + row] = s;
  else        up_f[w * 5120 + row] = s;
}

// ---------------------------------------------------------------------------
// Kernel 2: W_eff[n][k] = W[n][k] + sum_r up[n][r]*down[r][k], cast to bf16.
// ---------------------------------------------------------------------------
__global__ void build_weff(const float* __restrict__ Wq, const float* __restrict__ Wk,
                           const float* __restrict__ Wv, const float* __restrict__ Wo,
                           const float* __restrict__ down_f, const float* __restrict__ up_f,
                           u16* __restrict__ weff_qkv, u16* __restrict__ weff_o) {
  int tid = blockIdx.x * blockDim.x + threadIdx.x;  // 4 * 1638400
  int w = tid / 1638400;
  int rem = tid - w * 1638400;
  int n = rem / 1280;
  int k = rem - n * 1280;
  const float* W = (w == 0) ? Wq : (w == 1) ? Wk : (w == 2) ? Wv : Wo;
  const float* up = up_f + w * 5120 + n * 4;
  const float* dn = down_f + w * 5120 + k;
  float v = W[rem] + up[0] * dn[0] + up[1] * dn[1280] + up[2] * dn[2560] + up[3] * dn[3840];
  u16 hv = f2bf(v);
  if (w < 3) weff_qkv[w * 1638400 + rem] = hv;
  else       weff_o[rem] = hv;
}

// ---------------------------------------------------------------------------
// Kernel 3: x fp32 -> bf16
// ---------------------------------------------------------------------------
__global__ void cvt_x(const float4* __restrict__ x, ushort4* __restrict__ xb) {
  int i = blockIdx.x * blockDim.x + threadIdx.x;  // 1310720
  float4 v = x[i];
  ushort4 o;
  o.x = f2bf(v.x); o.y = f2bf(v.y); o.z = f2bf(v.z); o.w = f2bf(v.w);
  xb[i] = o;
}

// ---------------------------------------------------------------------------
// QKV GEMM: C[M,N] = A[M,K] @ B[N,K]^T.  128x128 tile, BK=64.  Staged tiles
// use a rotate-by-row k-chunk swizzle (slot pos p of row r holds global chunk
// (p+r)&7) making BK=64 fragment reads conflict-free.  LDS 32 KB.
// ---------------------------------------------------------------------------
__global__ __launch_bounds__(256) void gemm128_qkv(const u16* __restrict__ A, const u16* __restrict__ Bm,
                                                   u16* __restrict__ qb, u16* __restrict__ kb,
                                                   u16* __restrict__ vbuf, int K) {
  __shared__ __align__(16) u16 lA[128 * 64];
  __shared__ __align__(16) u16 lB[128 * 64];
  const int t = threadIdx.x;
  const int lane = t & 63;
  const int l15 = lane & 15, quad = lane >> 4;
  const int wid = t >> 6;
  const int wm = (wid >> 1) * 64;
  const int wn = (wid & 1) * 64;
  const int bm = blockIdx.x * 128;
  const int bn = blockIdx.y * 128;
  floatx4 acc[4][4] = {};

  // Staging slot -> global offset (slot c: row=c>>3, pos=c&7, chunk=(pos+row)&7).
  int soff[4];
#pragma unroll
  for (int i = 0; i < 4; ++i) {
    int c = t + i * 256;
    int row = c >> 3, pos = c & 7;
    soff[i] = row * K + ((pos + row) & 7) * 8;
  }
  // Fragment read offsets (tile-invariant): row r, k-chunk kc8 at pos (kc8-r)&7.
  int afo[4][2], bfo[4][2];
#pragma unroll
  for (int i = 0; i < 4; ++i) {
#pragma unroll
    for (int ch = 0; ch < 2; ++ch) {
      int ra = wm + i * 16 + l15;
      int rb = wn + i * 16 + l15;
      int kc8 = ch * 4 + quad;
      afo[i][ch] = ra * 64 + ((kc8 - ra) & 7) * 8;
      bfo[i][ch] = rb * 64 + ((kc8 - rb) & 7) * 8;
    }
  }

  const u16* Ab = A + (long)bm * K;
  const u16* Bb = Bm + (long)bn * K;
  const int nkt = K >> 6;

  for (int kt = 0; kt < nkt; ++kt) {
    __syncthreads();
    const int k0 = kt * 64;
#pragma unroll
    for (int i = 0; i < 4; ++i) gll16(Ab + (long)soff[i] + k0, lA + (t + i * 256) * 8);
#pragma unroll
    for (int i = 0; i < 4; ++i) gll16(Bb + (long)soff[i] + k0, lB + (t + i * 256) * 8);
    __syncthreads();
#pragma unroll
    for (int ch = 0; ch < 2; ++ch) {
      bf16x8 af[4], bfr[4];
#pragma unroll
      for (int i = 0; i < 4; ++i) af[i] = *(const bf16x8*)(lA + afo[i][ch]);
#pragma unroll
      for (int i = 0; i < 4; ++i) bfr[i] = *(const bf16x8*)(lB + bfo[i][ch]);
#pragma unroll
      for (int i = 0; i < 4; ++i)
#pragma unroll
        for (int j = 0; j < 4; ++j)
          acc[i][j] = MFMA_BF16(af[i], bfr[j], acc[i][j]);
    }
  }

#pragma unroll
  for (int i = 0; i < 4; ++i) {
#pragma unroll
    for (int j = 0; j < 4; ++j) {
#pragma unroll
      for (int r = 0; r < 4; ++r) {
        int m = bm + wm + i * 16 + quad * 4 + r;
        int n = bn + wn + j * 16 + l15;
        u16 hv = f2bf(acc[i][j][r]);
        if (n < 1280) {
          qb[(long)m * 1280 + n] = hv;
        } else if (n < 2560) {
          kb[(long)m * 1280 + (n - 1280)] = hv;
        } else {
          vbuf[(long)m * 1280 + (n - 2560)] = hv;  // natural, coalesced
        }
      }
    }
  }
}

// ---------------------------------------------------------------------------
// V transpose (scalar, verified R10): vbuf[(b*2048+s)][n] ->
// vtb[(b*1280+n)*2048 + s].  64x64 tiles, tile stride 65.
// ---------------------------------------------------------------------------
__global__ __launch_bounds__(256) void vtrans(const u16* __restrict__ vbuf,
                                              u16* __restrict__ vtb) {
  __shared__ u16 tile[64 * 65];
  const int t = threadIdx.x;
  const int sb = blockIdx.x * 64, nb = blockIdx.y * 64, b = blockIdx.z;
  const u16* src = vbuf + ((long)(b * 2048 + sb)) * 1280 + nb;
#pragma unroll
  for (int it = 0; it < 16; ++it) {
    int idx = t + it * 256;
    int s = idx >> 6, n = idx & 63;
    tile[s * 65 + n] = src[(long)s * 1280 + n];
  }
  __syncthreads();
  u16* dst = vtb + ((long)(b * 1280 + nb)) * 2048 + sb;
#pragma unroll
  for (int it = 0; it < 16; ++it) {
    int idx = t + it * 256;
    int n = idx >> 6, s = idx & 63;
    dst[(long)n * 2048 + s] = tile[s * 65 + n];
  }
}

// ---------------------------------------------------------------------------
// O-proj GEMM: 64x128 tile, BK=64 (20 iters), swizzled staging as above.
// LDS 24 KB.  fp32 out + bias.
// ---------------------------------------------------------------------------
__global__ __launch_bounds__(256) void gemm64_o(const u16* __restrict__ A, const u16* __restrict__ Bm,
                                                float* __restrict__ outf,
                                                const float* __restrict__ bias, int K) {
  __shared__ __align__(16) u16 lA[64 * 64];
  __shared__ __align__(16) u16 lB[128 * 64];
  const int t = threadIdx.x;
  const int lane = t & 63;
  const int l15 = lane & 15, quad = lane >> 4;
  const int wid = t >> 6;
  const int bm = blockIdx.x * 64;
  const int bn = blockIdx.y * 128;
  floatx4 acc[4][2] = {};

  int aoff[2], boff[4];
#pragma unroll
  for (int i = 0; i < 2; ++i) {
    int c = t + i * 256;
    int row = c >> 3, pos = c & 7;
    aoff[i] = row * K + ((pos + row) & 7) * 8;
  }
#pragma unroll
  for (int i = 0; i < 4; ++i) {
    int c = t + i * 256;
    int row = c >> 3, pos = c & 7;
    boff[i] = row * K + ((pos + row) & 7) * 8;
  }
  int afo[4][2], bfo[2][2];
#pragma unroll
  for (int ch = 0; ch < 2; ++ch) {
    int kc8 = ch * 4 + quad;
#pragma unroll
    for (int i = 0; i < 4; ++i) {
      int ra = i * 16 + l15;
      afo[i][ch] = ra * 64 + ((kc8 - ra) & 7) * 8;
    }
#pragma unroll
    for (int j = 0; j < 2; ++j) {
      int rb = wid * 32 + j * 16 + l15;
      bfo[j][ch] = rb * 64 + ((kc8 - rb) & 7) * 8;
    }
  }

  const u16* Ab = A + (long)bm * K;
  const u16* Bb = Bm + (long)bn * K;
  const int nkt = K >> 6;

  for (int kt = 0; kt < nkt; ++kt) {
    __syncthreads();
    const int k0 = kt * 64;
#pragma unroll
    for (int i = 0; i < 2; ++i) gll16(Ab + (long)aoff[i] + k0, lA + (t + i * 256) * 8);
#pragma unroll
    for (int i = 0; i < 4; ++i) gll16(Bb + (long)boff[i] + k0, lB + (t + i * 256) * 8);
    __syncthreads();
#pragma unroll
    for (int ch = 0; ch < 2; ++ch) {
      bf16x8 af[4], bfr[2];
#pragma unroll
      for (int i = 0; i < 4; ++i) af[i] = *(const bf16x8*)(lA + afo[i][ch]);
#pragma unroll
      for (int j = 0; j < 2; ++j) bfr[j] = *(const bf16x8*)(lB + bfo[j][ch]);
#pragma unroll
      for (int i = 0; i < 4; ++i)
#pragma unroll
        for (int j = 0; j < 2; ++j)
          acc[i][j] = MFMA_BF16(af[i], bfr[j], acc[i][j]);
    }
  }

#pragma unroll
  for (int i = 0; i < 4; ++i) {
#pragma unroll
    for (int j = 0; j < 2; ++j) {
#pragma unroll
      for (int r = 0; r < 4; ++r) {
        int m = bm + i * 16 + quad * 4 + r;
        int n = bn + wid * 32 + j * 16 + l15;
        outf[(long)m * 1280 + n] = acc[i][j][r] + bias[n];
      }
    }
  }
}

// ---------------------------------------------------------------------------
// Flash attention v6 (T12): swapped QK^T (S^T = K*Q^T) puts q = lane&31 in
// the C-layout, so each lane owns P for one q-row.  P -> PV A-frags built
// fully in-register: 8 v_cvt_pk_bf16_f32 + 4 permlane32_swap per tile
// (each swap yields two A-frag dwords).  Eliminates the per-tile P LDS
// round-trip (16 scatter ds_write_u16 + lgkmcnt(0) drain + 2 ds_reads) and
// all 16 f2bf.  l becomes a lane-local scalar.  p_lds deleted: LDS = 80 KB.
// Staging/double-buffer/vmcnt(5)/K-rotation/V-XOR identical to v5.
// Epilogue: 3-phase kh-pair reduce through reused kv_lds.
// ---------------------------------------------------------------------------
__global__ __launch_bounds__(512) void flash_attn(const u16* __restrict__ qb,
                                                  const u16* __restrict__ kb,
                                                  const u16* __restrict__ vtb,
                                                  u16* __restrict__ attn) {
  const int D = 1280, HD = 160;
  __shared__ __align__(16) u16 kv_lds[2][20480];  // K 10240 | V 10240 per buf
  const int t = threadIdx.x, lane = t & 63, wid = t >> 6;
  const int l31 = lane & 31, hi = lane >> 5;
  const int rg = wid >> 1, kh = wid & 1;
  const int bh = blockIdx.y, b = bh >> 3, h = bh & 7;
  const int q0 = blockIdx.x * 128 + rg * 32;
  const float kS = 0.11404582025f;

  // Q fragments (B-operand now): row q0+l31, d = kw*16 + hi*8 (+idx).
  bf16x8 aq[10];
  {
    const u16* qg = qb + ((long)(b * 2048 + q0 + l31)) * D + h * HD + hi * 8;
#pragma unroll
    for (int kw = 0; kw < 10; ++kw) aq[kw] = *(const bf16x8*)(qg + kw * 16);
  }

  // Staging sources (identical to v5): 2560 16B-chunks/tile.
  const u16* sg[5];
  int sadv[5];
#pragma unroll
  for (int i = 0; i < 5; ++i) {
    int c = t + i * 512;
    if (c < 1280) {
      int key = c / 20, pos = c - key * 20;
      int ccol = pos - (key % 20);
      if (ccol < 0) ccol += 20;
      sg[i] = kb + ((long)(b * 2048 + key)) * D + h * HD + ccol * 8;
      sadv[i] = 64 * D;
    } else {
      int c2 = c - 1280;
      int vrow = c2 >> 3, swz = c2 & 7;
      int vcol = swz ^ (vrow & 7);
      sg[i] = vtb + ((long)(b * 1280 + h * HD + vrow)) * 2048 + vcol * 8;
      sadv[i] = 64;
    }
  }

  // K fragment offsets (u16): key = kh*32+l31; global d-chunk g = kw*2+hi
  // stored at pos (g+key)%20.  (A-operand now; same per-lane reads.)
  int kfo[10];
  {
    int key = kh * 32 + l31;
#pragma unroll
    for (int kw = 0; kw < 10; ++kw) {
      int g = kw * 2 + hi;
      int pos = (g + key) % 20;
      kfo[kw] = (key * 20 + pos) * 8;
    }
  }
  // V fragment offsets (B-operand): d-row = db*32+l31; key-chunk
  // gc = kh*4+w*2+hi stored at swz = gc ^ (d&7).
  int vfo[5][2];
#pragma unroll
  for (int db = 0; db < 5; ++db) {
#pragma unroll
    for (int w = 0; w < 2; ++w) {
      int d = db * 32 + l31;
      int gc = kh * 4 + w * 2 + hi;
      int sw = gc ^ (d & 7);
      vfo[db][w] = 10240 + (d * 8 + sw) * 8;
    }
  }

  float l_sum = 0.f;
  floatx16 o_acc[5] = {};

  // Prologue: stage tile 0 into buffer 0.
#pragma unroll
  for (int i = 0; i < 5; ++i) {
    gll16(sg[i], &kv_lds[0][0] + (t + i * 512) * 8);
    sg[i] += sadv[i];
  }

  for (int kt0 = 0; kt0 < 32; ++kt0) {
    u16* cbase = &kv_lds[kt0 & 1][0];
    if (kt0 < 31) {
      u16* nbase = &kv_lds[(kt0 & 1) ^ 1][0];
#pragma unroll
      for (int i = 0; i < 5; ++i) {
        gll16(sg[i], nbase + (t + i * 512) * 8);
        sg[i] += sadv[i];
      }
      asm volatile("s_waitcnt vmcnt(5)" ::: "memory");
    } else {
      asm volatile("s_waitcnt vmcnt(0)" ::: "memory");
    }
    __builtin_amdgcn_s_barrier();
    __builtin_amdgcn_sched_barrier(0);

    // QK (swapped): S^T = K*Q^T, single 10-deep accumulate chain.
    floatx16 s = {};
#pragma unroll
    for (int kw = 0; kw < 10; ++kw) {
      bf16x8 kf = *(const bf16x8*)(cbase + kfo[kw]);
      s = MFMA32(kf, aq[kw], s);
    }

    // Softmax: lane owns q = l31; reg r holds key (r&3)+8*(r>>2)+4*hi.
    float p[16];
#pragma unroll
    for (int r = 0; r < 16; ++r) {
      p[r] = __builtin_exp2f(fminf(s[r] * kS, 80.f));
      l_sum += p[r];
    }

    // Pack to bf16 pairs (keys ascending within each pair).
    u32 c01 = cvtpk(p[0], p[1]),  c23 = cvtpk(p[2], p[3]);
    u32 c45 = cvtpk(p[4], p[5]),  c67 = cvtpk(p[6], p[7]);
    u32 c89 = cvtpk(p[8], p[9]),  cAB = cvtpk(p[10], p[11]);
    u32 cCD = cvtpk(p[12], p[13]), cEF = cvtpk(p[14], p[15]);

    // permlane32_swap: new_a = {a_lo, b_lo}, new_b = {a_hi, b_hi}.
    // Window 0 (local keys 0-15): dwords {w0,w1,w2,w3} per lane.
    u32x2 r02 = __builtin_amdgcn_permlane32_swap(c01, c45, false, false);
    u32x2 r13 = __builtin_amdgcn_permlane32_swap(c23, c67, false, false);
    u32x2 r46 = __builtin_amdgcn_permlane32_swap(c89, cCD, false, false);
    u32x2 r57 = __builtin_amdgcn_permlane32_swap(cAB, cEF, false, false);
    u32x4 pk0 = {r02[0], r13[0], r02[1], r13[1]};
    u32x4 pk1 = {r46[0], r57[0], r46[1], r57[1]};
    bf16x8 pa0 = __builtin_bit_cast(bf16x8, pk0);
    bf16x8 pa1 = __builtin_bit_cast(bf16x8, pk1);

    // PV: A = P (lane = q), B = V (lane = d-col); reads identical to v5.
#pragma unroll
    for (int db = 0; db < 5; ++db) {
      bf16x8 v0 = *(const bf16x8*)(cbase + vfo[db][0]);
      bf16x8 v1 = *(const bf16x8*)(cbase + vfo[db][1]);
      o_acc[db] = MFMA32(pa0, v0, o_acc[db]);
      o_acc[db] = MFMA32(pa1, v1, o_acc[db]);
    }
    __builtin_amdgcn_sched_barrier(0);
    __builtin_amdgcn_s_barrier();
  }

  // ---- Epilogue: 3-phase reduce through reused kv_lds. ----
  // Phase A: l partials [rg][kh][lane].
  float* lscr = (float*)&kv_lds[0][0];
  lscr[wid * 64 + lane] = l_sum;
  __syncthreads();
  float rl[16];
#pragma unroll
  for (int r = 0; r < 16; ++r) {
    int q32 = (r & 3) + 8 * (r >> 2) + 4 * hi;
    float tot = lscr[(rg * 2 + 0) * 64 + q32] + lscr[(rg * 2 + 0) * 64 + q32 + 32]
              + lscr[(rg * 2 + 1) * 64 + q32] + lscr[(rg * 2 + 1) * 64 + q32 + 32];
    rl[r] = 1.0f / tot;
  }
  __syncthreads();
  // Phase B: kh=1 dumps O partials (80 KB, exactly kv_lds).
  float* oscr = (float*)&kv_lds[0][0];
  if (kh == 1) {
#pragma unroll
    for (int db = 0; db < 5; ++db)
#pragma unroll
      for (int r = 0; r < 16; ++r)
        oscr[rg * 5120 + (db * 16 + r) * 64 + lane] = o_acc[db][r];
  }
  __syncthreads();
  // Phase C: kh=0 adds, normalizes, stores.
  if (kh == 0) {
#pragma unroll
    for (int db = 0; db < 5; ++db) {
#pragma unroll
      for (int r = 0; r < 16; ++r) {
        float v = (o_acc[db][r] + oscr[rg * 5120 + (db * 16 + r) * 64 + lane]) * rl[r];
        int row = q0 + (r & 3) + 8 * (r >> 2) + 4 * hi;
        int col = h * HD + db * 32 + l31;
        attn[((long)(b * 2048 + row)) * D + col] = f2bf(v);
      }
    }
  }
}

// ---------------------------------------------------------------------------
// Launcher.  Workspace (~76.2 MB):
//   xb @0 | weff_qkv @10485760 | weff_o @20316160 | qbuf @23592960
//   kbuf @34078720 | vtb @44564480 | attn @55050240 | down_f @65536000
//   up_f @65617920 | vbuf @65699840 (10485760)
// ---------------------------------------------------------------------------
extern "C" void kernel_launch(void* const* d_in, const int* in_sizes, int n_in,
                              void* d_out, int out_size, void* d_ws, size_t ws_size,
                              hipStream_t stream) {
  const float* x   = (const float*)d_in[0];
  const float* pal = (const float*)d_in[1];
  const float* Wq  = (const float*)d_in[2];
  const float* Wk  = (const float*)d_in[3];
  const float* Wv  = (const float*)d_in[4];
  const float* Wo  = (const float*)d_in[5];
  const float* bo  = (const float*)d_in[6];
  const float* qd  = (const float*)d_in[7];
  const float* qu  = (const float*)d_in[8];
  const float* kd  = (const float*)d_in[9];
  const float* ku  = (const float*)d_in[10];
  const float* vd  = (const float*)d_in[11];
  const float* vu  = (const float*)d_in[12];
  const float* od  = (const float*)d_in[13];
  const float* ou  = (const float*)d_in[14];
  float* out = (float*)d_out;

  char* ws = (char*)d_ws;
  u16* xb       = (u16*)(ws);
  u16* weff_qkv = (u16*)(ws + 10485760);
  u16* weff_o   = (u16*)(ws + 20316160);
  u16* qbuf     = (u16*)(ws + 23592960);
  u16* kbuf     = (u16*)(ws + 34078720);
  u16* vtb      = (u16*)(ws + 44564480);
  u16* attn     = (u16*)(ws + 55050240);
  float* down_f = (float*)(ws + 65536000);
  float* up_f   = (float*)(ws + 65617920);
  u16* vbuf     = (u16*)(ws + 65699840);

  prep_downup<<<160, 256, 0, stream>>>(pal, qd, qu, kd, ku, vd, vu, od, ou, down_f, up_f);
  build_weff<<<25600, 256, 0, stream>>>(Wq, Wk, Wv, Wo, down_f, up_f, weff_qkv, weff_o);
  cvt_x<<<5120, 256, 0, stream>>>((const float4*)x, (ushort4*)xb);
  gemm128_qkv<<<dim3(32, 30), 256, 0, stream>>>(xb, weff_qkv, qbuf, kbuf, vbuf, 1280);
  vtrans<<<dim3(32, 20, 2), 256, 0, stream>>>(vbuf, vtb);
  flash_attn<<<dim3(16, 16), 512, 0, stream>>>(qbuf, kbuf, vtb, attn);
  gemm64_o<<<dim3(64, 10), 256, 0, stream>>>(attn, weff_o, out, bo, 1280);
}

// Round 4
// 268.734 us; speedup vs baseline: 1.1303x; 1.0023x over previous
//
#include <hip/hip_runtime.h>

typedef unsigned short u16;
typedef unsigned int u32;
typedef __attribute__((ext_vector_type(4))) float floatx4;
typedef __attribute__((ext_vector_type(16))) float floatx16;
typedef __attribute__((ext_vector_type(8))) __bf16 bf16x8;
typedef __attribute__((ext_vector_type(2))) unsigned int u32x2;
typedef __attribute__((ext_vector_type(4))) unsigned int u32x4;

#define MFMA_BF16(a, b, c) __builtin_amdgcn_mfma_f32_16x16x32_bf16((a), (b), (c), 0, 0, 0)
#define MFMA32(a, b, c) __builtin_amdgcn_mfma_f32_32x32x16_bf16((a), (b), (c), 0, 0, 0)

typedef const __attribute__((address_space(1))) void* gas_ptr;
typedef __attribute__((address_space(3))) void* las_ptr;

__device__ __forceinline__ void gll16(const void* g, void* l) {
  __builtin_amdgcn_global_load_lds((gas_ptr)g, (las_ptr)l, 16, 0, 0);
}

__device__ __forceinline__ u16 f2bf(float x) {
  u32 u = __builtin_bit_cast(u32, x);
  u = (u + 0x7fffu + ((u >> 16) & 1u)) >> 16;
  return (u16)u;
}

__device__ __forceinline__ u32 cvtpk(float lo, float hi) {
  u32 r;
  asm("v_cvt_pk_bf16_f32 %0, %1, %2" : "=v"(r) : "v"(lo), "v"(hi));
  return r;
}

template <int WN>
__device__ __forceinline__ void vwait() {
  if constexpr (WN == 6) asm volatile("s_waitcnt vmcnt(6)" ::: "memory");
  else if constexpr (WN == 4) asm volatile("s_waitcnt vmcnt(4)" ::: "memory");
}

// ---------------------------------------------------------------------------
// Kernel 1: down/up vectors from palette.
// ---------------------------------------------------------------------------
__global__ void prep_downup(const float* __restrict__ pal,
                            const float* __restrict__ qd, const float* __restrict__ qu,
                            const float* __restrict__ kd, const float* __restrict__ ku,
                            const float* __restrict__ vd, const float* __restrict__ vu,
                            const float* __restrict__ od, const float* __restrict__ ou,
                            float* __restrict__ down_f, float* __restrict__ up_f) {
  int tid = blockIdx.x * blockDim.x + threadIdx.x;
  int w = tid / 10240;
  int rem = tid - w * 10240;
  const float* dsrc = (w == 0) ? qd : (w == 1) ? kd : (w == 2) ? vd : od;
  const float* usrc = (w == 0) ? qu : (w == 1) ? ku : (w == 2) ? vu : ou;
  bool isdown = rem < 5120;
  int row = isdown ? rem : rem - 5120;
  const float* src = (isdown ? dsrc : usrc) + row * 15;
  float s = 0.f;
#pragma unroll
  for (int p = 0; p < 15; ++p) s += pal[p] * src[p];
  if (isdown) down_f[w * 5120 + row] = s;
  else        up_f[w * 5120 + row] = s;
}

// ---------------------------------------------------------------------------
// Kernel 2: W_eff[n][k] = W[n][k] + sum_r up[n][r]*down[r][k], cast to bf16.
// ---------------------------------------------------------------------------
__global__ void build_weff(const float* __restrict__ Wq, const float* __restrict__ Wk,
                           const float* __restrict__ Wv, const float* __restrict__ Wo,
                           const float* __restrict__ down_f, const float* __restrict__ up_f,
                           u16* __restrict__ weff_qkv, u16* __restrict__ weff_o) {
  int tid = blockIdx.x * blockDim.x + threadIdx.x;  // 4 * 1638400
  int w = tid / 1638400;
  int rem = tid - w * 1638400;
  int n = rem / 1280;
  int k = rem - n * 1280;
  const float* W = (w == 0) ? Wq : (w == 1) ? Wk : (w == 2) ? Wv : Wo;
  const float* up = up_f + w * 5120 + n * 4;
  const float* dn = down_f + w * 5120 + k;
  float v = W[rem] + up[0] * dn[0] + up[1] * dn[1280] + up[2] * dn[2560] + up[3] * dn[3840];
  u16 hv = f2bf(v);
  if (w < 3) weff_qkv[w * 1638400 + rem] = hv;
  else       weff_o[rem] = hv;
}

// ---------------------------------------------------------------------------
// Kernel 3: x fp32 -> bf16
// ---------------------------------------------------------------------------
__global__ void cvt_x(const float4* __restrict__ x, ushort4* __restrict__ xb) {
  int i = blockIdx.x * blockDim.x + threadIdx.x;  // 1310720
  float4 v = x[i];
  ushort4 o;
  o.x = f2bf(v.x); o.y = f2bf(v.y); o.z = f2bf(v.z); o.w = f2bf(v.w);
  xb[i] = o;
}

// ---------------------------------------------------------------------------
// QKV GEMM v2: 256x256 tile, 8-phase schedule (T2+T3+T4+T5).  512 threads,
// 8 waves = 2 wm x 4 wn; per-wave output 128x64 (8x4 16x16 frags).  BK=64,
// 2 K-tiles per iteration.  LDS 128 KB: lA[2][256x64] + lB[2][256x64].
// Per phase: stage 1 half-tile (2 gll) -> counted vmcnt -> barrier ->
// 12 ds_read_b128 -> lgkmcnt(0) -> setprio(1) 16 MFMA setprio(0).
// Quadrant order q0=(A0,B0) q1=(A0,B1) q2=(A1,B0) q3=(A1,B1); half-tile
// stage order A0,B0,A1,B1 at distance-4 phases.  FIFO drain: vmcnt(6) at
// phases 0/4 (drains the 2 halves q0 needs), vmcnt(4) at 1/5, none at
// 2/3/6/7; queue bounded at 10.  Staging uses the proven rotate-by-row
// k-chunk swizzle (conflict-free, linear gll dest); fragment reads use the
// same (kc8-row)&7 formula (+mh*4096 / +nh*2048 for halves).
// Tail: i=9 phases 4-7 stage "tile 20" = reads a few KB past A/B into
// adjacent workspace buffers (valid memory, data never consumed).
// ---------------------------------------------------------------------------
__global__ __launch_bounds__(512) void gemm256_qkv(const u16* __restrict__ A, const u16* __restrict__ Bm,
                                                   u16* __restrict__ qb, u16* __restrict__ kb,
                                                   u16* __restrict__ vbuf, int K) {
  __shared__ __align__(16) u16 lA[2][16384];
  __shared__ __align__(16) u16 lB[2][16384];
  const int t = threadIdx.x;
  const int lane = t & 63;
  const int l15 = lane & 15, quad = lane >> 4;
  const int wid = t >> 6;
  const int wm = wid >> 2;   // 0..1 -> 128 rows
  const int wn = wid & 3;    // 0..3 -> 64 cols
  const int bm = blockIdx.x * 256;
  const int bn = blockIdx.y * 256;
  floatx4 acc[8][4] = {};

  // Staging: chunk c = h*1024 + t + j*512; row = c>>3, pos = t&7 (512,1024 = 0 mod 8).
  const int r0 = t >> 3, pos = t & 7;
  const long sof0 = (long)r0 * K + ((pos + r0) & 7) * 8;
  const long sof1 = (long)(r0 + 64) * K + ((pos + r0 + 64) & 7) * 8;

  // Fragment read offsets (u16 units), mh adds 4096, nh adds 2048.
  int afo[4][2], bfo[2][2];
#pragma unroll
  for (int ch = 0; ch < 2; ++ch) {
    int kc8 = ch * 4 + quad;
#pragma unroll
    for (int mi = 0; mi < 4; ++mi) {
      int ra = wm * 128 + mi * 16 + l15;
      afo[mi][ch] = ra * 64 + ((kc8 - ra) & 7) * 8;
    }
#pragma unroll
    for (int ni = 0; ni < 2; ++ni) {
      int rb = wn * 64 + ni * 16 + l15;
      bfo[ni][ch] = rb * 64 + ((kc8 - rb) & 7) * 8;
    }
  }

  const u16* Ab = A + (long)bm * K;
  const u16* Bb = Bm + (long)bn * K;

#define PHASE(CB, Q, SB, SMAT, SH, ST, WN)                                           \
  {                                                                                   \
    const u16* gsrc = (SMAT) ? Bb : Ab;                                               \
    u16* ld0 = ((SMAT) ? &lB[SB][0] : &lA[SB][0]) + ((SH) * 1024 + t) * 8;            \
    gll16(gsrc + sof0 + (long)(SH) * 128 * K + (long)(ST) * 64, ld0);                 \
    gll16(gsrc + sof1 + (long)(SH) * 128 * K + (long)(ST) * 64, ld0 + 4096);          \
    vwait<WN>();                                                                      \
    __builtin_amdgcn_s_barrier();                                                     \
    __builtin_amdgcn_sched_barrier(0);                                                \
    constexpr int mh = (Q) >> 1, nh = (Q) & 1;                                        \
    bf16x8 af[4][2], bfr[2][2];                                                       \
    _Pragma("unroll") for (int ch = 0; ch < 2; ++ch) {                                \
      _Pragma("unroll") for (int mi = 0; mi < 4; ++mi)                                \
        af[mi][ch] = *(const bf16x8*)(&lA[CB][0] + afo[mi][ch] + mh * 4096);          \
      _Pragma("unroll") for (int ni = 0; ni < 2; ++ni)                                \
        bfr[ni][ch] = *(const bf16x8*)(&lB[CB][0] + bfo[ni][ch] + nh * 2048);         \
    }                                                                                 \
    asm volatile("s_waitcnt lgkmcnt(0)" ::: "memory");                                \
    __builtin_amdgcn_sched_barrier(0);                                                \
    __builtin_amdgcn_s_setprio(1);                                                    \
    _Pragma("unroll") for (int ch = 0; ch < 2; ++ch)                                  \
      _Pragma("unroll") for (int mi = 0; mi < 4; ++mi)                                \
        _Pragma("unroll") for (int ni = 0; ni < 2; ++ni)                              \
          acc[mh * 4 + mi][nh * 2 + ni] =                                             \
              MFMA_BF16(af[mi][ch], bfr[ni][ch], acc[mh * 4 + mi][nh * 2 + ni]);      \
    __builtin_amdgcn_s_setprio(0);                                                    \
  }

  // Prologue: stage tile 0 into buf0, FIFO order A0,B0,A1,B1.
  gll16(Ab + sof0, &lA[0][t * 8]);
  gll16(Ab + sof1, &lA[0][t * 8 + 4096]);
  gll16(Bb + sof0, &lB[0][t * 8]);
  gll16(Bb + sof1, &lB[0][t * 8 + 4096]);
  gll16(Ab + sof0 + 128L * K, &lA[0][(1024 + t) * 8]);
  gll16(Ab + sof1 + 128L * K, &lA[0][(1024 + t) * 8 + 4096]);
  gll16(Bb + sof0 + 128L * K, &lB[0][(1024 + t) * 8]);
  gll16(Bb + sof1 + 128L * K, &lB[0][(1024 + t) * 8 + 4096]);

  const int niter = K >> 7;  // 2 K-tiles per iteration
  for (int i = 0; i < niter; ++i) {
    const int t1 = 2 * i + 1, t2 = 2 * i + 2;
    PHASE(0, 0, 1, 0, 0, t1, 6);
    PHASE(0, 1, 1, 1, 0, t1, 4);
    PHASE(0, 2, 1, 0, 1, t1, 0);
    PHASE(0, 3, 1, 1, 1, t1, 0);
    PHASE(1, 0, 0, 0, 0, t2, 6);
    PHASE(1, 1, 0, 1, 0, t2, 4);
    PHASE(1, 2, 0, 0, 1, t2, 0);
    PHASE(1, 3, 0, 1, 1, t2, 0);
  }
#undef PHASE
  asm volatile("s_waitcnt vmcnt(0)" ::: "memory");

#pragma unroll
  for (int mi8 = 0; mi8 < 8; ++mi8) {
#pragma unroll
    for (int ni4 = 0; ni4 < 4; ++ni4) {
#pragma unroll
      for (int r = 0; r < 4; ++r) {
        int m = bm + wm * 128 + (mi8 >> 2) * 64 + (mi8 & 3) * 16 + quad * 4 + r;
        int n = bn + wn * 64 + (ni4 >> 1) * 32 + (ni4 & 1) * 16 + l15;
        u16 hv = f2bf(acc[mi8][ni4][r]);
        if (n < 1280) {
          qb[(long)m * 1280 + n] = hv;
        } else if (n < 2560) {
          kb[(long)m * 1280 + (n - 1280)] = hv;
        } else {
          vbuf[(long)m * 1280 + (n - 2560)] = hv;
        }
      }
    }
  }
}

// ---------------------------------------------------------------------------
// V transpose (scalar, verified R10): vbuf[(b*2048+s)][n] ->
// vtb[(b*1280+n)*2048 + s].  64x64 tiles, tile stride 65.
// ---------------------------------------------------------------------------
__global__ __launch_bounds__(256) void vtrans(const u16* __restrict__ vbuf,
                                              u16* __restrict__ vtb) {
  __shared__ u16 tile[64 * 65];
  const int t = threadIdx.x;
  const int sb = blockIdx.x * 64, nb = blockIdx.y * 64, b = blockIdx.z;
  const u16* src = vbuf + ((long)(b * 2048 + sb)) * 1280 + nb;
#pragma unroll
  for (int it = 0; it < 16; ++it) {
    int idx = t + it * 256;
    int s = idx >> 6, n = idx & 63;
    tile[s * 65 + n] = src[(long)s * 1280 + n];
  }
  __syncthreads();
  u16* dst = vtb + ((long)(b * 1280 + nb)) * 2048 + sb;
#pragma unroll
  for (int it = 0; it < 16; ++it) {
    int idx = t + it * 256;
    int n = idx >> 6, s = idx & 63;
    dst[(long)n * 2048 + s] = tile[s * 65 + n];
  }
}

// ---------------------------------------------------------------------------
// O-proj GEMM v2: 128x128 tile (proven m97-style structure, was 64x128),
// BK=64, rotate-by-row swizzled staging, fp32 out + bias.  Grid (32,10).
// ---------------------------------------------------------------------------
__global__ __launch_bounds__(256) void gemm128_o(const u16* __restrict__ A, const u16* __restrict__ Bm,
                                                 float* __restrict__ outf,
                                                 const float* __restrict__ bias, int K) {
  __shared__ __align__(16) u16 lA[128 * 64];
  __shared__ __align__(16) u16 lB[128 * 64];
  const int t = threadIdx.x;
  const int lane = t & 63;
  const int l15 = lane & 15, quad = lane >> 4;
  const int wid = t >> 6;
  const int wm = (wid >> 1) * 64;
  const int wn = (wid & 1) * 64;
  const int bm = blockIdx.x * 128;
  const int bn = blockIdx.y * 128;
  floatx4 acc[4][4] = {};

  int soff[4];
#pragma unroll
  for (int i = 0; i < 4; ++i) {
    int c = t + i * 256;
    int row = c >> 3, pos = c & 7;
    soff[i] = row * K + ((pos + row) & 7) * 8;
  }
  int afo[4][2], bfo[4][2];
#pragma unroll
  for (int i = 0; i < 4; ++i) {
#pragma unroll
    for (int ch = 0; ch < 2; ++ch) {
      int ra = wm + i * 16 + l15;
      int rb = wn + i * 16 + l15;
      int kc8 = ch * 4 + quad;
      afo[i][ch] = ra * 64 + ((kc8 - ra) & 7) * 8;
      bfo[i][ch] = rb * 64 + ((kc8 - rb) & 7) * 8;
    }
  }

  const u16* Ab = A + (long)bm * K;
  const u16* Bb = Bm + (long)bn * K;
  const int nkt = K >> 6;

  for (int kt = 0; kt < nkt; ++kt) {
    __syncthreads();
    const int k0 = kt * 64;
#pragma unroll
    for (int i = 0; i < 4; ++i) gll16(Ab + (long)soff[i] + k0, lA + (t + i * 256) * 8);
#pragma unroll
    for (int i = 0; i < 4; ++i) gll16(Bb + (long)soff[i] + k0, lB + (t + i * 256) * 8);
    __syncthreads();
#pragma unroll
    for (int ch = 0; ch < 2; ++ch) {
      bf16x8 af[4], bfr[4];
#pragma unroll
      for (int i = 0; i < 4; ++i) af[i] = *(const bf16x8*)(lA + afo[i][ch]);
#pragma unroll
      for (int i = 0; i < 4; ++i) bfr[i] = *(const bf16x8*)(lB + bfo[i][ch]);
#pragma unroll
      for (int i = 0; i < 4; ++i)
#pragma unroll
        for (int j = 0; j < 4; ++j)
          acc[i][j] = MFMA_BF16(af[i], bfr[j], acc[i][j]);
    }
  }

#pragma unroll
  for (int i = 0; i < 4; ++i) {
#pragma unroll
    for (int j = 0; j < 4; ++j) {
#pragma unroll
      for (int r = 0; r < 4; ++r) {
        int m = bm + wm + i * 16 + quad * 4 + r;
        int n = bn + wn + j * 16 + l15;
        outf[(long)m * 1280 + n] = acc[i][j][r] + bias[n];
      }
    }
  }
}

// ---------------------------------------------------------------------------
// Flash attention v7 = v6 + setprio(1) around QK and PV MFMA clusters (T5).
// ---------------------------------------------------------------------------
__global__ __launch_bounds__(512) void flash_attn(const u16* __restrict__ qb,
                                                  const u16* __restrict__ kb,
                                                  const u16* __restrict__ vtb,
                                                  u16* __restrict__ attn) {
  const int D = 1280, HD = 160;
  __shared__ __align__(16) u16 kv_lds[2][20480];  // K 10240 | V 10240 per buf
  const int t = threadIdx.x, lane = t & 63, wid = t >> 6;
  const int l31 = lane & 31, hi = lane >> 5;
  const int rg = wid >> 1, kh = wid & 1;
  const int bh = blockIdx.y, b = bh >> 3, h = bh & 7;
  const int q0 = blockIdx.x * 128 + rg * 32;
  const float kS = 0.11404582025f;

  bf16x8 aq[10];
  {
    const u16* qg = qb + ((long)(b * 2048 + q0 + l31)) * D + h * HD + hi * 8;
#pragma unroll
    for (int kw = 0; kw < 10; ++kw) aq[kw] = *(const bf16x8*)(qg + kw * 16);
  }

  const u16* sg[5];
  int sadv[5];
#pragma unroll
  for (int i = 0; i < 5; ++i) {
    int c = t + i * 512;
    if (c < 1280) {
      int key = c / 20, pos = c - key * 20;
      int ccol = pos - (key % 20);
      if (ccol < 0) ccol += 20;
      sg[i] = kb + ((long)(b * 2048 + key)) * D + h * HD + ccol * 8;
      sadv[i] = 64 * D;
    } else {
      int c2 = c - 1280;
      int vrow = c2 >> 3, swz = c2 & 7;
      int vcol = swz ^ (vrow & 7);
      sg[i] = vtb + ((long)(b * 1280 + h * HD + vrow)) * 2048 + vcol * 8;
      sadv[i] = 64;
    }
  }

  int kfo[10];
  {
    int key = kh * 32 + l31;
#pragma unroll
    for (int kw = 0; kw < 10; ++kw) {
      int g = kw * 2 + hi;
      int pos = (g + key) % 20;
      kfo[kw] = (key * 20 + pos) * 8;
    }
  }
  int vfo[5][2];
#pragma unroll
  for (int db = 0; db < 5; ++db) {
#pragma unroll
    for (int w = 0; w < 2; ++w) {
      int d = db * 32 + l31;
      int gc = kh * 4 + w * 2 + hi;
      int sw = gc ^ (d & 7);
      vfo[db][w] = 10240 + (d * 8 + sw) * 8;
    }
  }

  float l_sum = 0.f;
  floatx16 o_acc[5] = {};

#pragma unroll
  for (int i = 0; i < 5; ++i) {
    gll16(sg[i], &kv_lds[0][0] + (t + i * 512) * 8);
    sg[i] += sadv[i];
  }

  for (int kt0 = 0; kt0 < 32; ++kt0) {
    u16* cbase = &kv_lds[kt0 & 1][0];
    if (kt0 < 31) {
      u16* nbase = &kv_lds[(kt0 & 1) ^ 1][0];
#pragma unroll
      for (int i = 0; i < 5; ++i) {
        gll16(sg[i], nbase + (t + i * 512) * 8);
        sg[i] += sadv[i];
      }
      asm volatile("s_waitcnt vmcnt(5)" ::: "memory");
    } else {
      asm volatile("s_waitcnt vmcnt(0)" ::: "memory");
    }
    __builtin_amdgcn_s_barrier();
    __builtin_amdgcn_sched_barrier(0);

    floatx16 s = {};
    __builtin_amdgcn_s_setprio(1);
#pragma unroll
    for (int kw = 0; kw < 10; ++kw) {
      bf16x8 kf = *(const bf16x8*)(cbase + kfo[kw]);
      s = MFMA32(kf, aq[kw], s);
    }
    __builtin_amdgcn_s_setprio(0);

    float p[16];
#pragma unroll
    for (int r = 0; r < 16; ++r) {
      p[r] = __builtin_exp2f(fminf(s[r] * kS, 80.f));
      l_sum += p[r];
    }

    u32 c01 = cvtpk(p[0], p[1]),  c23 = cvtpk(p[2], p[3]);
    u32 c45 = cvtpk(p[4], p[5]),  c67 = cvtpk(p[6], p[7]);
    u32 c89 = cvtpk(p[8], p[9]),  cAB = cvtpk(p[10], p[11]);
    u32 cCD = cvtpk(p[12], p[13]), cEF = cvtpk(p[14], p[15]);

    u32x2 r02 = __builtin_amdgcn_permlane32_swap(c01, c45, false, false);
    u32x2 r13 = __builtin_amdgcn_permlane32_swap(c23, c67, false, false);
    u32x2 r46 = __builtin_amdgcn_permlane32_swap(c89, cCD, false, false);
    u32x2 r57 = __builtin_amdgcn_permlane32_swap(cAB, cEF, false, false);
    u32x4 pk0 = {r02[0], r13[0], r02[1], r13[1]};
    u32x4 pk1 = {r46[0], r57[0], r46[1], r57[1]};
    bf16x8 pa0 = __builtin_bit_cast(bf16x8, pk0);
    bf16x8 pa1 = __builtin_bit_cast(bf16x8, pk1);

    __builtin_amdgcn_s_setprio(1);
#pragma unroll
    for (int db = 0; db < 5; ++db) {
      bf16x8 v0 = *(const bf16x8*)(cbase + vfo[db][0]);
      bf16x8 v1 = *(const bf16x8*)(cbase + vfo[db][1]);
      o_acc[db] = MFMA32(pa0, v0, o_acc[db]);
      o_acc[db] = MFMA32(pa1, v1, o_acc[db]);
    }
    __builtin_amdgcn_s_setprio(0);
    __builtin_amdgcn_sched_barrier(0);
    __builtin_amdgcn_s_barrier();
  }

  // ---- Epilogue: 3-phase reduce through reused kv_lds. ----
  float* lscr = (float*)&kv_lds[0][0];
  lscr[wid * 64 + lane] = l_sum;
  __syncthreads();
  float rl[16];
#pragma unroll
  for (int r = 0; r < 16; ++r) {
    int q32 = (r & 3) + 8 * (r >> 2) + 4 * hi;
    float tot = lscr[(rg * 2 + 0) * 64 + q32] + lscr[(rg * 2 + 0) * 64 + q32 + 32]
              + lscr[(rg * 2 + 1) * 64 + q32] + lscr[(rg * 2 + 1) * 64 + q32 + 32];
    rl[r] = 1.0f / tot;
  }
  __syncthreads();
  float* oscr = (float*)&kv_lds[0][0];
  if (kh == 1) {
#pragma unroll
    for (int db = 0; db < 5; ++db)
#pragma unroll
      for (int r = 0; r < 16; ++r)
        oscr[rg * 5120 + (db * 16 + r) * 64 + lane] = o_acc[db][r];
  }
  __syncthreads();
  if (kh == 0) {
#pragma unroll
    for (int db = 0; db < 5; ++db) {
#pragma unroll
      for (int r = 0; r < 16; ++r) {
        float v = (o_acc[db][r] + oscr[rg * 5120 + (db * 16 + r) * 64 + lane]) * rl[r];
        int row = q0 + (r & 3) + 8 * (r >> 2) + 4 * hi;
        int col = h * HD + db * 32 + l31;
        attn[((long)(b * 2048 + row)) * D + col] = f2bf(v);
      }
    }
  }
}

// ---------------------------------------------------------------------------
// Launcher.  Workspace (~76.2 MB):
//   xb @0 | weff_qkv @10485760 | weff_o @20316160 | qbuf @23592960
//   kbuf @34078720 | vtb @44564480 | attn @55050240 | down_f @65536000
//   up_f @65617920 | vbuf @65699840 (10485760)
// ---------------------------------------------------------------------------
extern "C" void kernel_launch(void* const* d_in, const int* in_sizes, int n_in,
                              void* d_out, int out_size, void* d_ws, size_t ws_size,
                              hipStream_t stream) {
  const float* x   = (const float*)d_in[0];
  const float* pal = (const float*)d_in[1];
  const float* Wq  = (const float*)d_in[2];
  const float* Wk  = (const float*)d_in[3];
  const float* Wv  = (const float*)d_in[4];
  const float* Wo  = (const float*)d_in[5];
  const float* bo  = (const float*)d_in[6];
  const float* qd  = (const float*)d_in[7];
  const float* qu  = (const float*)d_in[8];
  const float* kd  = (const float*)d_in[9];
  const float* ku  = (const float*)d_in[10];
  const float* vd  = (const float*)d_in[11];
  const float* vu  = (const float*)d_in[12];
  const float* od  = (const float*)d_in[13];
  const float* ou  = (const float*)d_in[14];
  float* out = (float*)d_out;

  char* ws = (char*)d_ws;
  u16* xb       = (u16*)(ws);
  u16* weff_qkv = (u16*)(ws + 10485760);
  u16* weff_o   = (u16*)(ws + 20316160);
  u16* qbuf     = (u16*)(ws + 23592960);
  u16* kbuf     = (u16*)(ws + 34078720);
  u16* vtb      = (u16*)(ws + 44564480);
  u16* attn     = (u16*)(ws + 55050240);
  float* down_f = (float*)(ws + 65536000);
  float* up_f   = (float*)(ws + 65617920);
  u16* vbuf     = (u16*)(ws + 65699840);

  prep_downup<<<160, 256, 0, stream>>>(pal, qd, qu, kd, ku, vd, vu, od, ou, down_f, up_f);
  build_weff<<<25600, 256, 0, stream>>>(Wq, Wk, Wv, Wo, down_f, up_f, weff_qkv, weff_o);
  cvt_x<<<5120, 256, 0, stream>>>((const float4*)x, (ushort4*)xb);
  gemm256_qkv<<<dim3(16, 15), 512, 0, stream>>>(xb, weff_qkv, qbuf, kbuf, vbuf, 1280);
  vtrans<<<dim3(32, 20, 2), 256, 0, stream>>>(vbuf, vtb);
  flash_attn<<<dim3(16, 16), 512, 0, stream>>>(qbuf, kbuf, vtb, attn);
  gemm128_o<<<dim3(32, 10), 256, 0, stream>>>(attn, weff_o, out, bo, 1280);
}

// Round 5
// 267.517 us; speedup vs baseline: 1.1354x; 1.0045x over previous
//
#include <hip/hip_runtime.h>

typedef unsigned short u16;
typedef unsigned int u32;
typedef __attribute__((ext_vector_type(4))) float floatx4;
typedef __attribute__((ext_vector_type(16))) float floatx16;
typedef __attribute__((ext_vector_type(8))) __bf16 bf16x8;
typedef __attribute__((ext_vector_type(2))) unsigned int u32x2;
typedef __attribute__((ext_vector_type(4))) unsigned int u32x4;

#define MFMA_BF16(a, b, c) __builtin_amdgcn_mfma_f32_16x16x32_bf16((a), (b), (c), 0, 0, 0)
#define MFMA32(a, b, c) __builtin_amdgcn_mfma_f32_32x32x16_bf16((a), (b), (c), 0, 0, 0)

typedef const __attribute__((address_space(1))) void* gas_ptr;
typedef __attribute__((address_space(3))) void* las_ptr;

__device__ __forceinline__ void gll16(const void* g, void* l) {
  __builtin_amdgcn_global_load_lds((gas_ptr)g, (las_ptr)l, 16, 0, 0);
}

__device__ __forceinline__ u16 f2bf(float x) {
  u32 u = __builtin_bit_cast(u32, x);
  u = (u + 0x7fffu + ((u >> 16) & 1u)) >> 16;
  return (u16)u;
}

__device__ __forceinline__ u32 cvtpk(float lo, float hi) {
  u32 r;
  asm("v_cvt_pk_bf16_f32 %0, %1, %2" : "=v"(r) : "v"(lo), "v"(hi));
  return r;
}

template <int WN>
__device__ __forceinline__ void vwait() {
  if constexpr (WN == 6) asm volatile("s_waitcnt vmcnt(6)" ::: "memory");
  else if constexpr (WN == 4) asm volatile("s_waitcnt vmcnt(4)" ::: "memory");
}

// ---------------------------------------------------------------------------
// Kernel 1: down/up vectors from palette.
// ---------------------------------------------------------------------------
__global__ void prep_downup(const float* __restrict__ pal,
                            const float* __restrict__ qd, const float* __restrict__ qu,
                            const float* __restrict__ kd, const float* __restrict__ ku,
                            const float* __restrict__ vd, const float* __restrict__ vu,
                            const float* __restrict__ od, const float* __restrict__ ou,
                            float* __restrict__ down_f, float* __restrict__ up_f) {
  int tid = blockIdx.x * blockDim.x + threadIdx.x;
  int w = tid / 10240;
  int rem = tid - w * 10240;
  const float* dsrc = (w == 0) ? qd : (w == 1) ? kd : (w == 2) ? vd : od;
  const float* usrc = (w == 0) ? qu : (w == 1) ? ku : (w == 2) ? vu : ou;
  bool isdown = rem < 5120;
  int row = isdown ? rem : rem - 5120;
  const float* src = (isdown ? dsrc : usrc) + row * 15;
  float s = 0.f;
#pragma unroll
  for (int p = 0; p < 15; ++p) s += pal[p] * src[p];
  if (isdown) down_f[w * 5120 + row] = s;
  else        up_f[w * 5120 + row] = s;
}

// ---------------------------------------------------------------------------
// Kernel 2: W_eff[n][k] = W[n][k] + sum_r up[n][r]*down[r][k], cast to bf16.
// ---------------------------------------------------------------------------
__global__ void build_weff(const float* __restrict__ Wq, const float* __restrict__ Wk,
                           const float* __restrict__ Wv, const float* __restrict__ Wo,
                           const float* __restrict__ down_f, const float* __restrict__ up_f,
                           u16* __restrict__ weff_qkv, u16* __restrict__ weff_o) {
  int tid = blockIdx.x * blockDim.x + threadIdx.x;  // 4 * 1638400
  int w = tid / 1638400;
  int rem = tid - w * 1638400;
  int n = rem / 1280;
  int k = rem - n * 1280;
  const float* W = (w == 0) ? Wq : (w == 1) ? Wk : (w == 2) ? Wv : Wo;
  const float* up = up_f + w * 5120 + n * 4;
  const float* dn = down_f + w * 5120 + k;
  float v = W[rem] + up[0] * dn[0] + up[1] * dn[1280] + up[2] * dn[2560] + up[3] * dn[3840];
  u16 hv = f2bf(v);
  if (w < 3) weff_qkv[w * 1638400 + rem] = hv;
  else       weff_o[rem] = hv;
}

// ---------------------------------------------------------------------------
// Kernel 3: x fp32 -> bf16
// ---------------------------------------------------------------------------
__global__ void cvt_x(const float4* __restrict__ x, ushort4* __restrict__ xb) {
  int i = blockIdx.x * blockDim.x + threadIdx.x;  // 1310720
  float4 v = x[i];
  ushort4 o;
  o.x = f2bf(v.x); o.y = f2bf(v.y); o.z = f2bf(v.z); o.w = f2bf(v.w);
  xb[i] = o;
}

// ---------------------------------------------------------------------------
// QKV GEMM v2: 256x256 tile, 8-phase schedule (T2+T3+T4+T5) + XCD swizzle
// (240 = 8 XCDs x 30, bijective; same-B-panel blocks share an XCD L2).
// ---------------------------------------------------------------------------
__global__ __launch_bounds__(512) void gemm256_qkv(const u16* __restrict__ A, const u16* __restrict__ Bm,
                                                   u16* __restrict__ qb, u16* __restrict__ kb,
                                                   u16* __restrict__ vbuf, int K) {
  __shared__ __align__(16) u16 lA[2][16384];
  __shared__ __align__(16) u16 lB[2][16384];
  const int t = threadIdx.x;
  const int lane = t & 63;
  const int l15 = lane & 15, quad = lane >> 4;
  const int wid = t >> 6;
  const int wm = wid >> 2;   // 0..1 -> 128 rows
  const int wn = wid & 3;    // 0..3 -> 64 cols
  // XCD swizzle: l = by*16+bx in [0,240); v = (l%8)*30 + l/8 (bijective).
  const int l = blockIdx.y * 16 + blockIdx.x;
  const int v = (l & 7) * 30 + (l >> 3);
  const int bm = (v & 15) * 256;
  const int bn = (v >> 4) * 256;
  floatx4 acc[8][4] = {};

  const int r0 = t >> 3, pos = t & 7;
  const long sof0 = (long)r0 * K + ((pos + r0) & 7) * 8;
  const long sof1 = (long)(r0 + 64) * K + ((pos + r0 + 64) & 7) * 8;

  int afo[4][2], bfo[2][2];
#pragma unroll
  for (int ch = 0; ch < 2; ++ch) {
    int kc8 = ch * 4 + quad;
#pragma unroll
    for (int mi = 0; mi < 4; ++mi) {
      int ra = wm * 128 + mi * 16 + l15;
      afo[mi][ch] = ra * 64 + ((kc8 - ra) & 7) * 8;
    }
#pragma unroll
    for (int ni = 0; ni < 2; ++ni) {
      int rb = wn * 64 + ni * 16 + l15;
      bfo[ni][ch] = rb * 64 + ((kc8 - rb) & 7) * 8;
    }
  }

  const u16* Ab = A + (long)bm * K;
  const u16* Bb = Bm + (long)bn * K;

#define PHASE(CB, Q, SB, SMAT, SH, ST, WN)                                           \
  {                                                                                   \
    const u16* gsrc = (SMAT) ? Bb : Ab;                                               \
    u16* ld0 = ((SMAT) ? &lB[SB][0] : &lA[SB][0]) + ((SH) * 1024 + t) * 8;            \
    gll16(gsrc + sof0 + (long)(SH) * 128 * K + (long)(ST) * 64, ld0);                 \
    gll16(gsrc + sof1 + (long)(SH) * 128 * K + (long)(ST) * 64, ld0 + 4096);          \
    vwait<WN>();                                                                      \
    __builtin_amdgcn_s_barrier();                                                     \
    __builtin_amdgcn_sched_barrier(0);                                                \
    constexpr int mh = (Q) >> 1, nh = (Q) & 1;                                        \
    bf16x8 af[4][2], bfr[2][2];                                                       \
    _Pragma("unroll") for (int ch = 0; ch < 2; ++ch) {                                \
      _Pragma("unroll") for (int mi = 0; mi < 4; ++mi)                                \
        af[mi][ch] = *(const bf16x8*)(&lA[CB][0] + afo[mi][ch] + mh * 4096);          \
      _Pragma("unroll") for (int ni = 0; ni < 2; ++ni)                                \
        bfr[ni][ch] = *(const bf16x8*)(&lB[CB][0] + bfo[ni][ch] + nh * 2048);         \
    }                                                                                 \
    asm volatile("s_waitcnt lgkmcnt(0)" ::: "memory");                                \
    __builtin_amdgcn_sched_barrier(0);                                                \
    __builtin_amdgcn_s_setprio(1);                                                    \
    _Pragma("unroll") for (int ch = 0; ch < 2; ++ch)                                  \
      _Pragma("unroll") for (int mi = 0; mi < 4; ++mi)                                \
        _Pragma("unroll") for (int ni = 0; ni < 2; ++ni)                              \
          acc[mh * 4 + mi][nh * 2 + ni] =                                             \
              MFMA_BF16(af[mi][ch], bfr[ni][ch], acc[mh * 4 + mi][nh * 2 + ni]);      \
    __builtin_amdgcn_s_setprio(0);                                                    \
  }

  gll16(Ab + sof0, &lA[0][t * 8]);
  gll16(Ab + sof1, &lA[0][t * 8 + 4096]);
  gll16(Bb + sof0, &lB[0][t * 8]);
  gll16(Bb + sof1, &lB[0][t * 8 + 4096]);
  gll16(Ab + sof0 + 128L * K, &lA[0][(1024 + t) * 8]);
  gll16(Ab + sof1 + 128L * K, &lA[0][(1024 + t) * 8 + 4096]);
  gll16(Bb + sof0 + 128L * K, &lB[0][(1024 + t) * 8]);
  gll16(Bb + sof1 + 128L * K, &lB[0][(1024 + t) * 8 + 4096]);

  const int niter = K >> 7;  // 2 K-tiles per iteration
  for (int i = 0; i < niter; ++i) {
    const int t1 = 2 * i + 1, t2 = 2 * i + 2;
    PHASE(0, 0, 1, 0, 0, t1, 6);
    PHASE(0, 1, 1, 1, 0, t1, 4);
    PHASE(0, 2, 1, 0, 1, t1, 0);
    PHASE(0, 3, 1, 1, 1, t1, 0);
    PHASE(1, 0, 0, 0, 0, t2, 6);
    PHASE(1, 1, 0, 1, 0, t2, 4);
    PHASE(1, 2, 0, 0, 1, t2, 0);
    PHASE(1, 3, 0, 1, 1, t2, 0);
  }
#undef PHASE
  asm volatile("s_waitcnt vmcnt(0)" ::: "memory");

#pragma unroll
  for (int mi8 = 0; mi8 < 8; ++mi8) {
#pragma unroll
    for (int ni4 = 0; ni4 < 4; ++ni4) {
#pragma unroll
      for (int r = 0; r < 4; ++r) {
        int m = bm + wm * 128 + (mi8 >> 2) * 64 + (mi8 & 3) * 16 + quad * 4 + r;
        int n = bn + wn * 64 + (ni4 >> 1) * 32 + (ni4 & 1) * 16 + l15;
        u16 hv = f2bf(acc[mi8][ni4][r]);
        if (n < 1280) {
          qb[(long)m * 1280 + n] = hv;
        } else if (n < 2560) {
          kb[(long)m * 1280 + (n - 1280)] = hv;
        } else {
          vbuf[(long)m * 1280 + (n - 2560)] = hv;
        }
      }
    }
  }
}

// ---------------------------------------------------------------------------
// V transpose (scalar, verified R10): vbuf[(b*2048+s)][n] ->
// vtb[(b*1280+n)*2048 + s].  64x64 tiles, tile stride 65.
// ---------------------------------------------------------------------------
__global__ __launch_bounds__(256) void vtrans(const u16* __restrict__ vbuf,
                                              u16* __restrict__ vtb) {
  __shared__ u16 tile[64 * 65];
  const int t = threadIdx.x;
  const int sb = blockIdx.x * 64, nb = blockIdx.y * 64, b = blockIdx.z;
  const u16* src = vbuf + ((long)(b * 2048 + sb)) * 1280 + nb;
#pragma unroll
  for (int it = 0; it < 16; ++it) {
    int idx = t + it * 256;
    int s = idx >> 6, n = idx & 63;
    tile[s * 65 + n] = src[(long)s * 1280 + n];
  }
  __syncthreads();
  u16* dst = vtb + ((long)(b * 1280 + nb)) * 2048 + sb;
#pragma unroll
  for (int it = 0; it < 16; ++it) {
    int idx = t + it * 256;
    int n = idx >> 6, s = idx & 63;
    dst[(long)n * 2048 + s] = tile[s * 65 + n];
  }
}

// ---------------------------------------------------------------------------
// O-proj GEMM v2: 128x128 tile, BK=64, rotate-by-row swizzled staging,
// fp32 out + bias.  Grid (32,10).
// ---------------------------------------------------------------------------
__global__ __launch_bounds__(256) void gemm128_o(const u16* __restrict__ A, const u16* __restrict__ Bm,
                                                 float* __restrict__ outf,
                                                 const float* __restrict__ bias, int K) {
  __shared__ __align__(16) u16 lA[128 * 64];
  __shared__ __align__(16) u16 lB[128 * 64];
  const int t = threadIdx.x;
  const int lane = t & 63;
  const int l15 = lane & 15, quad = lane >> 4;
  const int wid = t >> 6;
  const int wm = (wid >> 1) * 64;
  const int wn = (wid & 1) * 64;
  const int bm = blockIdx.x * 128;
  const int bn = blockIdx.y * 128;
  floatx4 acc[4][4] = {};

  int soff[4];
#pragma unroll
  for (int i = 0; i < 4; ++i) {
    int c = t + i * 256;
    int row = c >> 3, pos = c & 7;
    soff[i] = row * K + ((pos + row) & 7) * 8;
  }
  int afo[4][2], bfo[4][2];
#pragma unroll
  for (int i = 0; i < 4; ++i) {
#pragma unroll
    for (int ch = 0; ch < 2; ++ch) {
      int ra = wm + i * 16 + l15;
      int rb = wn + i * 16 + l15;
      int kc8 = ch * 4 + quad;
      afo[i][ch] = ra * 64 + ((kc8 - ra) & 7) * 8;
      bfo[i][ch] = rb * 64 + ((kc8 - rb) & 7) * 8;
    }
  }

  const u16* Ab = A + (long)bm * K;
  const u16* Bb = Bm + (long)bn * K;
  const int nkt = K >> 6;

  for (int kt = 0; kt < nkt; ++kt) {
    __syncthreads();
    const int k0 = kt * 64;
#pragma unroll
    for (int i = 0; i < 4; ++i) gll16(Ab + (long)soff[i] + k0, lA + (t + i * 256) * 8);
#pragma unroll
    for (int i = 0; i < 4; ++i) gll16(Bb + (long)soff[i] + k0, lB + (t + i * 256) * 8);
    __syncthreads();
#pragma unroll
    for (int ch = 0; ch < 2; ++ch) {
      bf16x8 af[4], bfr[4];
#pragma unroll
      for (int i = 0; i < 4; ++i) af[i] = *(const bf16x8*)(lA + afo[i][ch]);
#pragma unroll
      for (int i = 0; i < 4; ++i) bfr[i] = *(const bf16x8*)(lB + bfo[i][ch]);
#pragma unroll
      for (int i = 0; i < 4; ++i)
#pragma unroll
        for (int j = 0; j < 4; ++j)
          acc[i][j] = MFMA_BF16(af[i], bfr[j], acc[i][j]);
    }
  }

#pragma unroll
  for (int i = 0; i < 4; ++i) {
#pragma unroll
    for (int j = 0; j < 4; ++j) {
#pragma unroll
      for (int r = 0; r < 4; ++r) {
        int m = bm + wm + i * 16 + quad * 4 + r;
        int n = bn + wn + j * 16 + l15;
        outf[(long)m * 1280 + n] = acc[i][j][r] + bias[n];
      }
    }
  }
}

// ---------------------------------------------------------------------------
// Flash attention v8 (T15 + rot3 + XCD swizzle):
// - Cross-tile pipeline: per iter, QK(t) then {PV(t-1) MFMA || softmax(t)
//   VALU} as independent streams.  2 LDS buffers suffice via split staging:
//   K(t+1) and V(t) issued at iter-t top (V write separated from PV(t-2)
//   reads by the iter t-1 end barrier).  Per-wave 5 gll/iter -> steady
//   vmcnt(5) drains prior tile's K and V exactly.
// - K rotation multiplier 3: bank start = 28*key mod 32 -> 8 distinct
//   starts (was 2) -> ~4x fewer K-read conflicts.
// - XCD swizzle (256 = 8x32): all 16 q-blocks of one (b,h) on one XCD.
// LDS 80 KB.
// ---------------------------------------------------------------------------
__global__ __launch_bounds__(512) void flash_attn(const u16* __restrict__ qb,
                                                  const u16* __restrict__ kb,
                                                  const u16* __restrict__ vtb,
                                                  u16* __restrict__ attn) {
  const int D = 1280, HD = 160;
  __shared__ __align__(16) u16 kv_lds[2][20480];  // K 10240 | V 10240 per buf
  const int t = threadIdx.x, lane = t & 63, wid = t >> 6;
  const int l31 = lane & 31, hi = lane >> 5;
  const int rg = wid >> 1, kh = wid & 1;
  // XCD swizzle: l in [0,256); v = (l%8)*32 + l/8 (bijective).
  const int lflat = blockIdx.y * 16 + blockIdx.x;
  const int vswz = (lflat & 7) * 32 + (lflat >> 3);
  const int qi = vswz & 15, bh = vswz >> 4;
  const int b = bh >> 3, h = bh & 7;
  const int q0 = qi * 128 + rg * 32;
  const float kS = 0.11404582025f;

  bf16x8 aq[10];
  {
    const u16* qg = qb + ((long)(b * 2048 + q0 + l31)) * D + h * HD + hi * 8;
#pragma unroll
    for (int kw = 0; kw < 10; ++kw) aq[kw] = *(const bf16x8*)(qg + kw * 16);
  }

  // Staging sources: chunk c = t + i*512.  c<1280: K (key=c/20, slot pos
  // holds global chunk g=(pos-3*key)%20).  c>=1280: V (XOR swizzle).
  const u16* sg[5];
  int sadv[5];
#pragma unroll
  for (int i = 0; i < 5; ++i) {
    int c = t + i * 512;
    if (c < 1280) {
      int key = c / 20, pos = c - key * 20;
      int g = pos - (3 * key) % 20;
      if (g < 0) g += 20;
      sg[i] = kb + ((long)(b * 2048 + key)) * D + h * HD + g * 8;
      sadv[i] = 64 * D;
    } else {
      int c2 = c - 1280;
      int vrow = c2 >> 3, swz = c2 & 7;
      int vcol = swz ^ (vrow & 7);
      sg[i] = vtb + ((long)(b * 1280 + h * HD + vrow)) * 2048 + vcol * 8;
      sadv[i] = 64;
    }
  }

  // K fragment offsets: key = kh*32+l31, g = kw*2+hi at pos (g+3*key)%20.
  int kfo[10];
  {
    int key = kh * 32 + l31;
    int r3 = (3 * key) % 20;
#pragma unroll
    for (int kw = 0; kw < 10; ++kw) {
      int g = kw * 2 + hi;
      int pos = g + r3;
      if (pos >= 20) pos -= 20;
      kfo[kw] = (key * 20 + pos) * 8;
    }
  }
  int vfo[5][2];
#pragma unroll
  for (int db = 0; db < 5; ++db) {
#pragma unroll
    for (int w = 0; w < 2; ++w) {
      int d = db * 32 + l31;
      int gc = kh * 4 + w * 2 + hi;
      int sw = gc ^ (d & 7);
      vfo[db][w] = 10240 + (d * 8 + sw) * 8;
    }
  }

  float l_sum = 0.f;
  floatx16 o_acc[5] = {};
  bf16x8 paA = {}, paB = {};

  // Prologue: stage K(0) into buf0 (K-part only), advance K pointers.
  gll16(sg[0], &kv_lds[0][t * 8]);           sg[0] += sadv[0];
  gll16(sg[1], &kv_lds[0][(t + 512) * 8]);   sg[1] += sadv[1];
  if (wid < 4) { gll16(sg[2], &kv_lds[0][(t + 1024) * 8]); sg[2] += sadv[2]; }

  for (int kt0 = 0; kt0 < 32; ++kt0) {
    u16* kd = &kv_lds[(kt0 + 1) & 1][0];
    u16* vd = &kv_lds[kt0 & 1][0];
    // K(t+1)
    if (kt0 < 31) {
      gll16(sg[0], kd + t * 8);          sg[0] += sadv[0];
      gll16(sg[1], kd + (t + 512) * 8);  sg[1] += sadv[1];
      if (wid < 4) { gll16(sg[2], kd + (t + 1024) * 8); sg[2] += sadv[2]; }
    }
    // V(t)
    if (wid >= 4) { gll16(sg[2], vd + (t + 1024) * 8); sg[2] += sadv[2]; }
    gll16(sg[3], vd + (t + 1536) * 8);  sg[3] += sadv[3];
    gll16(sg[4], vd + (t + 2048) * 8);  sg[4] += sadv[4];

    if (kt0 < 31) asm volatile("s_waitcnt vmcnt(5)" ::: "memory");
    else          asm volatile("s_waitcnt vmcnt(0)" ::: "memory");
    __builtin_amdgcn_s_barrier();
    __builtin_amdgcn_sched_barrier(0);

    const u16* kbase = &kv_lds[kt0 & 1][0];
    const u16* vbase = &kv_lds[(kt0 + 1) & 1][0];  // holds V(t-1)

    // QK(t): two 5-deep chains.
    floatx16 s0 = {}, s1 = {};
#pragma unroll
    for (int kw = 0; kw < 5; ++kw) {
      bf16x8 k0 = *(const bf16x8*)(kbase + kfo[kw * 2]);
      bf16x8 k1 = *(const bf16x8*)(kbase + kfo[kw * 2 + 1]);
      s0 = MFMA32(k0, aq[kw * 2], s0);
      s1 = MFMA32(k1, aq[kw * 2 + 1], s1);
    }

    // PV(t-1): independent of s0/s1 -> overlaps with softmax below.
    if (kt0 > 0) {
#pragma unroll
      for (int db = 0; db < 5; ++db) {
        bf16x8 v0 = *(const bf16x8*)(vbase + vfo[db][0]);
        bf16x8 v1 = *(const bf16x8*)(vbase + vfo[db][1]);
        o_acc[db] = MFMA32(paA, v0, o_acc[db]);
        o_acc[db] = MFMA32(paB, v1, o_acc[db]);
      }
    }

    // softmax(t) + pack -> new paA/paB.
    float p[16];
#pragma unroll
    for (int r = 0; r < 16; ++r) {
      p[r] = __builtin_exp2f(fminf((s0[r] + s1[r]) * kS, 80.f));
      l_sum += p[r];
    }
    u32 c01 = cvtpk(p[0], p[1]),  c23 = cvtpk(p[2], p[3]);
    u32 c45 = cvtpk(p[4], p[5]),  c67 = cvtpk(p[6], p[7]);
    u32 c89 = cvtpk(p[8], p[9]),  cAB = cvtpk(p[10], p[11]);
    u32 cCD = cvtpk(p[12], p[13]), cEF = cvtpk(p[14], p[15]);
    u32x2 r02 = __builtin_amdgcn_permlane32_swap(c01, c45, false, false);
    u32x2 r13 = __builtin_amdgcn_permlane32_swap(c23, c67, false, false);
    u32x2 r46 = __builtin_amdgcn_permlane32_swap(c89, cCD, false, false);
    u32x2 r57 = __builtin_amdgcn_permlane32_swap(cAB, cEF, false, false);
    u32x4 pk0 = {r02[0], r13[0], r02[1], r13[1]};
    u32x4 pk1 = {r46[0], r57[0], r46[1], r57[1]};
    paA = __builtin_bit_cast(bf16x8, pk0);
    paB = __builtin_bit_cast(bf16x8, pk1);

    __builtin_amdgcn_sched_barrier(0);
    __builtin_amdgcn_s_barrier();
  }

  // Drain: PV(31) from buffer 1 (V(31) landed via vmcnt(0)+barrier).
  {
    const u16* vbase = &kv_lds[1][0];
#pragma unroll
    for (int db = 0; db < 5; ++db) {
      bf16x8 v0 = *(const bf16x8*)(vbase + vfo[db][0]);
      bf16x8 v1 = *(const bf16x8*)(vbase + vfo[db][1]);
      o_acc[db] = MFMA32(paA, v0, o_acc[db]);
      o_acc[db] = MFMA32(paB, v1, o_acc[db]);
    }
  }
  __syncthreads();

  // ---- Epilogue: 3-phase reduce through reused kv_lds. ----
  float* lscr = (float*)&kv_lds[0][0];
  lscr[wid * 64 + lane] = l_sum;
  __syncthreads();
  float rl[16];
#pragma unroll
  for (int r = 0; r < 16; ++r) {
    int q32 = (r & 3) + 8 * (r >> 2) + 4 * hi;
    float tot = lscr[(rg * 2 + 0) * 64 + q32] + lscr[(rg * 2 + 0) * 64 + q32 + 32]
              + lscr[(rg * 2 + 1) * 64 + q32] + lscr[(rg * 2 + 1) * 64 + q32 + 32];
    rl[r] = 1.0f / tot;
  }
  __syncthreads();
  float* oscr = (float*)&kv_lds[0][0];
  if (kh == 1) {
#pragma unroll
    for (int db = 0; db < 5; ++db)
#pragma unroll
      for (int r = 0; r < 16; ++r)
        oscr[rg * 5120 + (db * 16 + r) * 64 + lane] = o_acc[db][r];
  }
  __syncthreads();
  if (kh == 0) {
#pragma unroll
    for (int db = 0; db < 5; ++db) {
#pragma unroll
      for (int r = 0; r < 16; ++r) {
        float v = (o_acc[db][r] + oscr[rg * 5120 + (db * 16 + r) * 64 + lane]) * rl[r];
        int row = q0 + (r & 3) + 8 * (r >> 2) + 4 * hi;
        int col = h * HD + db * 32 + l31;
        attn[((long)(b * 2048 + row)) * D + col] = f2bf(v);
      }
    }
  }
}

// ---------------------------------------------------------------------------
// Launcher.  Workspace (~76.2 MB):
//   xb @0 | weff_qkv @10485760 | weff_o @20316160 | qbuf @23592960
//   kbuf @34078720 | vtb @44564480 | attn @55050240 | down_f @65536000
//   up_f @65617920 | vbuf @65699840 (10485760)
// ---------------------------------------------------------------------------
extern "C" void kernel_launch(void* const* d_in, const int* in_sizes, int n_in,
                              void* d_out, int out_size, void* d_ws, size_t ws_size,
                              hipStream_t stream) {
  const float* x   = (const float*)d_in[0];
  const float* pal = (const float*)d_in[1];
  const float* Wq  = (const float*)d_in[2];
  const float* Wk  = (const float*)d_in[3];
  const float* Wv  = (const float*)d_in[4];
  const float* Wo  = (const float*)d_in[5];
  const float* bo  = (const float*)d_in[6];
  const float* qd  = (const float*)d_in[7];
  const float* qu  = (const float*)d_in[8];
  const float* kd  = (const float*)d_in[9];
  const float* ku  = (const float*)d_in[10];
  const float* vd  = (const float*)d_in[11];
  const float* vu  = (const float*)d_in[12];
  const float* od  = (const float*)d_in[13];
  const float* ou  = (const float*)d_in[14];
  float* out = (float*)d_out;

  char* ws = (char*)d_ws;
  u16* xb       = (u16*)(ws);
  u16* weff_qkv = (u16*)(ws + 10485760);
  u16* weff_o   = (u16*)(ws + 20316160);
  u16* qbuf     = (u16*)(ws + 23592960);
  u16* kbuf     = (u16*)(ws + 34078720);
  u16* vtb      = (u16*)(ws + 44564480);
  u16* attn     = (u16*)(ws + 55050240);
  float* down_f = (float*)(ws + 65536000);
  float* up_f   = (float*)(ws + 65617920);
  u16* vbuf     = (u16*)(ws + 65699840);

  prep_downup<<<160, 256, 0, stream>>>(pal, qd, qu, kd, ku, vd, vu, od, ou, down_f, up_f);
  build_weff<<<25600, 256, 0, stream>>>(Wq, Wk, Wv, Wo, down_f, up_f, weff_qkv, weff_o);
  cvt_x<<<5120, 256, 0, stream>>>((const float4*)x, (ushort4*)xb);
  gemm256_qkv<<<dim3(16, 15), 512, 0, stream>>>(xb, weff_qkv, qbuf, kbuf, vbuf, 1280);
  vtrans<<<dim3(32, 20, 2), 256, 0, stream>>>(vbuf, vtb);
  flash_attn<<<dim3(16, 16), 512, 0, stream>>>(qbuf, kbuf, vtb, attn);
  gemm128_o<<<dim3(32, 10), 256, 0, stream>>>(attn, weff_o, out, bo, 1280);
}